// Round 12
// baseline (283.546 us; speedup 1.0000x reference)
//
#include <hip/hip_runtime.h>

typedef __attribute__((ext_vector_type(4))) float f32x4;
typedef __attribute__((ext_vector_type(8))) short bf16x8;

#define NCH 25088   // static bins (>= N2=25000), multiple of 4
#define NCHK 128    // histogram chunks

__device__ __forceinline__ unsigned short f32_to_bf16_rne(float f){
  unsigned u = __builtin_bit_cast(unsigned, f);
  unsigned r = u + 0x7FFFu + ((u >> 16) & 1u);
  return (unsigned short)(r >> 16);
}
__device__ __forceinline__ float bf16_hi_to_f32(unsigned short h){
  unsigned u = ((unsigned)h) << 16;
  return __builtin_bit_cast(float, u);
}
__device__ __forceinline__ float blo(unsigned u){ return bf16_hi_to_f32((unsigned short)(u & 0xFFFF)); }
__device__ __forceinline__ float bhi(unsigned u){ return bf16_hi_to_f32((unsigned short)(u >> 16)); }
__device__ __forceinline__ float leakyf(float v){ return v > 0.f ? v : 0.01f*v; }
__device__ __forceinline__ unsigned f32_ord(float f){
  unsigned u = __builtin_bit_cast(unsigned, f);
  return (u & 0x80000000u) ? ~u : (u | 0x80000000u);
}

// ---------------- weight pre-split into MFMA B-fragment layout (hi/lo bf16) -------------
__global__ void prep_w_kernel(const float* __restrict__ W, short* __restrict__ Wh,
                              short* __restrict__ Wl, int K, int N)
{
  int total = K*N;
  int NF = N >> 4;
  for (int i = blockIdx.x*blockDim.x + threadIdx.x; i < total; i += gridDim.x*blockDim.x){
    int k = i / N, n = i % N;
    float w = W[i];
    unsigned short h = f32_to_bf16_rne(w);
    unsigned short l = f32_to_bf16_rne(w - bf16_hi_to_f32(h));
    int kb = k >> 5, kr = k & 31, cb = n >> 4;
    int lanei = ((kr >> 3) << 4) | (n & 15);
    size_t dst = (((size_t)(kb*NF + cb))*64 + lanei)*8 + (kr & 7);
    Wh[dst] = (short)h; Wl[dst] = (short)l;
  }
}

// ---------------- fused chunk histogram, u8-packed LDS (75KB), 512 thr, 128 chunks ------
__global__ __launch_bounds__(512) void hist_kernel(const int* __restrict__ ei,
                                                   unsigned short* __restrict__ lrank,
                                                   unsigned* __restrict__ Hc32,
                                                   unsigned short* __restrict__ RH16,
                                                   unsigned* __restrict__ intra,
                                                   int E, int CS, int N2)
{
  __shared__ unsigned ccnt[NCH/4];
  __shared__ unsigned rcnt[NCH/2];
  int tid = threadIdx.x;
  for (int i = tid; i < NCH/4; i += 512) ccnt[i] = 0;
  for (int i = tid; i < NCH/2; i += 512) rcnt[i] = 0;
  __syncthreads();
  int s = blockIdx.x*CS, eend = min(E, s + CS);
  for (int e = s + tid; e < eend; e += 512){
    int r = ei[e], c = ei[E+e];
    int rp = r >> 1;
    atomicAdd(&rcnt[rp>>1], 1u << (((rp & 1) << 4) + ((r & 1) << 3)));
    int cb = c >> 1;
    int sh = (cb & 3) << 3;
    unsigned old = atomicAdd(&ccnt[cb>>2], 1u << sh);
    lrank[e] = (unsigned short)((old >> sh) & 0xFFu);
    if (rp == cb) atomicAdd(&intra[rp], 1u);
  }
  __syncthreads();
  unsigned* hc = Hc32 + (size_t)blockIdx.x*(N2 >> 2);
  for (int i = tid; i < (N2 >> 2); i += 512) hc[i] = ccnt[i];
  unsigned* rh32 = (unsigned*)(RH16 + (size_t)blockIdx.x*N2);
  for (int i = tid; i < (N2 >> 1); i += 512) rh32[i] = rcnt[i];
}

// ---------------- per-bin chunk-offset prefix + bin totals (4 bins/thread) --------------
__global__ void co_scan_kernel(const unsigned* __restrict__ Hc32,
                               unsigned short* __restrict__ CO,
                               int* __restrict__ colTotal, int N2)
{
  int q = blockIdx.x*blockDim.x + threadIdx.x;   // bins 4q..4q+3
  if (q >= (N2 >> 2)) return;
  unsigned a0=0,a1=0,a2=0,a3=0;
  for (int ch = 0; ch < NCHK; ++ch){
    unsigned v = Hc32[(size_t)ch*(N2>>2) + q];
    ushort4 co = {(unsigned short)a0,(unsigned short)a1,(unsigned short)a2,(unsigned short)a3};
    *(ushort4*)(CO + (size_t)ch*N2 + 4*q) = co;
    a0 += v & 0xFFu; a1 += (v>>8) & 0xFFu; a2 += (v>>16) & 0xFFu; a3 += (v>>24) & 0xFFu;
  }
  int4 ct = {(int)a0,(int)a1,(int)a2,(int)a3};
  *(int4*)(colTotal + 4*q) = ct;
}

// ---------------- dis from chunked row histograms (u16 packed even8|odd8) ---------------
__global__ void dis_kernel(const unsigned short* __restrict__ RH16,
                           const unsigned* __restrict__ intra,
                           float* __restrict__ dis0, float* __restrict__ dis1, int N2)
{
  int p = blockIdx.x*blockDim.x + threadIdx.x;
  if (p >= N2) return;
  unsigned se = 0, so = 0;
  for (int ch = 0; ch < NCHK; ++ch){
    unsigned v = RH16[(size_t)ch*N2 + p];
    se += v & 0xFFu; so += (v >> 8) & 0xFFu;
  }
  float2 d0 = { rsqrtf((float)se + 1.0f), rsqrtf((float)so + 1.0f) };
  *(float2*)(dis0 + 2*p) = d0;
  dis1[p] = rsqrtf((float)(se + so - intra[p]) + 1.0f);
}

// ---------------- 3-pass parallel exclusive scan over colTotal -------------------------
__global__ void scan_partial_kernel(const int* __restrict__ cnt, int* __restrict__ bsum, int N)
{
  __shared__ int ws[4];
  int t = threadIdx.x, lane = t & 63, wv = t >> 6;
  int i = blockIdx.x*256 + t;
  int v = (i < N) ? cnt[i] : 0;
#pragma unroll
  for (int d = 1; d < 64; d <<= 1) v += __shfl_xor(v, d);
  if (lane == 0) ws[wv] = v;
  __syncthreads();
  if (t == 0) bsum[blockIdx.x] = ws[0]+ws[1]+ws[2]+ws[3];
}

__global__ void scan_bsums_kernel(int* __restrict__ bsum, int NB)
{
  int lane = threadIdx.x;  // 64 threads, 1 wave
  int carry = 0;
  for (int base = 0; base < NB; base += 64){
    int i = base + lane;
    int v = (i < NB) ? bsum[i] : 0;
    int x = v;
#pragma unroll
    for (int d = 1; d < 64; d <<= 1){
      int y = __shfl_up(x, d);
      if (lane >= d) x += y;
    }
    if (i < NB) bsum[i] = x - v + carry;   // exclusive
    carry += __shfl(x, 63);
  }
}

__global__ void scan_final_kernel(const int* __restrict__ cnt, const int* __restrict__ bsum,
                                  int* __restrict__ starts, int N)
{
  __shared__ int wsum[4];
  int t = threadIdx.x, lane = t & 63, wv = t >> 6;
  int i = blockIdx.x*256 + t;
  int v = (i < N) ? cnt[i] : 0;
  int x = v;
#pragma unroll
  for (int d = 1; d < 64; d <<= 1){
    int y = __shfl_up(x, d);
    if (lane >= d) x += y;
  }
  if (lane == 63) wsum[wv] = x;
  __syncthreads();
  int woff = 0;
#pragma unroll
  for (int j = 0; j < 4; j++) if (j < wv) woff += wsum[j];
  int base = bsum[blockIdx.x] + woff;
  if (i < N) starts[i+1] = base + x;
  if (blockIdx.x == 0 && t == 0) starts[0] = 0;
}

// ---------------- CSR fill: 2 edges/thread, one 16B AoS store per edge ------------------
__global__ void fill_kernel(const int* __restrict__ ei, const float* __restrict__ ea,
                            const float* __restrict__ We0, const float* __restrict__ be0,
                            const float* __restrict__ We1, const float* __restrict__ be1,
                            const int* __restrict__ starts,
                            const unsigned short* __restrict__ lrank,
                            const unsigned short* __restrict__ CO,
                            uint4* __restrict__ payload,
                            int E, int CS, int N2)
{
  float A0[12], A1[12];
#pragma unroll
  for (int i=0;i<12;i++){ A0[i]=We0[i]; A1[i]=We1[i]; }
  float b0 = be0[0], b1 = be1[0];
  int e0 = (blockIdx.x*blockDim.x + threadIdx.x)*2;
  if (e0 >= E) return;
  int e1 = e0 + 1;
  bool has1 = e1 < E;
  int ra = ei[e0], ca = ei[E+e0];
  int rb = has1 ? ei[e1] : 0, cb = has1 ? ei[E+e1] : 0;
  const f32x4* apa = (const f32x4*)(ea + (size_t)e0*12);
  const f32x4* apb = (const f32x4*)(ea + (size_t)e1*12);
  f32x4 va0 = apa[0], va1 = apa[1], va2 = apa[2];
  f32x4 vb0, vb1, vb2;
  if (has1){ vb0 = apb[0]; vb1 = apb[1]; vb2 = apb[2]; }
  float sa0 = b0, sa1 = b1, sb0 = b0, sb1 = b1;
#pragma unroll
  for (int j=0;j<4;j++){ sa0 += va0[j]*A0[j];   sa1 += va0[j]*A1[j]; }
#pragma unroll
  for (int j=0;j<4;j++){ sa0 += va1[j]*A0[4+j]; sa1 += va1[j]*A1[4+j]; }
#pragma unroll
  for (int j=0;j<4;j++){ sa0 += va2[j]*A0[8+j]; sa1 += va2[j]*A1[8+j]; }
  {
    int bin = ca >> 1, ch = e0 / CS;
    int pos = starts[bin] + (int)CO[(size_t)ch*N2 + bin] + (int)lrank[e0];
    uint4 pay = { (unsigned)(ra | ((ca & 1) << 31)),
                  __builtin_bit_cast(unsigned, sa0),
                  __builtin_bit_cast(unsigned, sa1), 0u };
    payload[pos] = pay;
  }
  if (has1){
#pragma unroll
    for (int j=0;j<4;j++){ sb0 += vb0[j]*A0[j];   sb1 += vb0[j]*A1[j]; }
#pragma unroll
    for (int j=0;j<4;j++){ sb0 += vb1[j]*A0[4+j]; sb1 += vb1[j]*A1[4+j]; }
#pragma unroll
    for (int j=0;j<4;j++){ sb0 += vb2[j]*A0[8+j]; sb1 += vb2[j]*A1[8+j]; }
    int bin = cb >> 1, ch = e1 / CS;
    int pos = starts[bin] + (int)CO[(size_t)ch*N2 + bin] + (int)lrank[e1];
    uint4 pay = { (unsigned)(rb | ((cb & 1) << 31)),
                  __builtin_bit_cast(unsigned, sb0),
                  __builtin_bit_cast(unsigned, sb1), 0u };
    payload[pos] = pay;
  }
}

// ---------------- split-bf16 MFMA GEMM: Y = epilogue(X @ W + b) -------------------------
// flags&1: y = leaky(y*scale + shift);  flags&2: store bf16;  flags&4: y *= rowscale[row]
template<int NF>
__global__ __launch_bounds__(256) void gemm_split(
    const float* __restrict__ X, const short* __restrict__ Wh, const short* __restrict__ Wl,
    const float* __restrict__ bias, const float* __restrict__ scale, const float* __restrict__ shift,
    const float* __restrict__ rowscale,
    void* __restrict__ Yv, int M, int K, int flags)
{
  const int Nn = NF*16;
  int w = threadIdx.x >> 6, lane = threadIdx.x & 63;
  int r0 = blockIdx.x*64 + w*16;
  int arow = r0 + (lane & 15);
  long arow_c = (arow < M) ? arow : (M-1);
  int kHi = (lane >> 4) << 3;
  f32x4 acc[NF];
#pragma unroll
  for (int i=0;i<NF;i++){
#pragma unroll
    for (int j=0;j<4;j++) acc[i][j] = 0.f;
  }
  int KB = K >> 5;
  const float* aprow = X + arow_c*(long)K + kHi;
  for (int kb=0; kb<KB; ++kb){
    const float* ap = aprow + kb*32;
    f32x4 a0 = *(const f32x4*)ap;
    f32x4 a1 = *(const f32x4*)(ap+4);
    bf16x8 ah, al;
#pragma unroll
    for (int j=0;j<8;j++){
      float f = (j<4) ? a0[j] : a1[j-4];
      unsigned short h = f32_to_bf16_rne(f);
      ah[j] = (short)h;
      al[j] = (short)f32_to_bf16_rne(f - bf16_hi_to_f32(h));
    }
    const short* bp  = Wh + ((size_t)kb*NF*64 + lane)*8;
    const short* bpl = Wl + ((size_t)kb*NF*64 + lane)*8;
#pragma unroll
    for (int cb=0; cb<NF; ++cb){
      bf16x8 bh = *(const bf16x8*)(bp  + (size_t)cb*512);
      bf16x8 bl = *(const bf16x8*)(bpl + (size_t)cb*512);
      acc[cb] = __builtin_amdgcn_mfma_f32_16x16x32_bf16(ah, bh, acc[cb], 0,0,0);
      acc[cb] = __builtin_amdgcn_mfma_f32_16x16x32_bf16(al, bh, acc[cb], 0,0,0);
      acc[cb] = __builtin_amdgcn_mfma_f32_16x16x32_bf16(ah, bl, acc[cb], 0,0,0);
    }
  }
  int crow = r0 + ((lane >> 4) << 2);
  int ccol = lane & 15;
  float rw[4] = {1.f,1.f,1.f,1.f};
  if (flags & 4){
#pragma unroll
    for (int r=0;r<4;r++) if (crow + r < M) rw[r] = rowscale[crow + r];
  }
  float* Yf = (float*)Yv;
  unsigned short* Yb = (unsigned short*)Yv;
#pragma unroll
  for (int cb=0; cb<NF; ++cb){
    int c = cb*16 + ccol;
    float b = bias[c];
    float sc = 1.f, sh = 0.f;
    if (flags & 1){ sc = scale[c]; sh = shift[c]; }
#pragma unroll
    for (int r=0;r<4;r++){
      int row = crow + r;
      if (row < M){
        float v = acc[cb][r] + b;
        if (flags & 1){ v = v*sc + sh; v = leakyf(v); }
        if (flags & 4) v *= rw[r];
        if (flags & 2) Yb[(size_t)row*Nn + c] = f32_to_bf16_rne(v);
        else           Yf[(size_t)row*Nn + c] = v;
      }
    }
  }
}

// accumulate one uint4 (8 bf16 cols) into 8 named scalars with coefficient c
#define ACC8(u, c, a0,a1,a2,a3,a4,a5,a6,a7) \
  a0 += (c)*blo((u).x); a1 += (c)*bhi((u).x); \
  a2 += (c)*blo((u).y); a3 += (c)*bhi((u).y); \
  a4 += (c)*blo((u).z); a5 += (c)*bhi((u).z); \
  a6 += (c)*blo((u).w); a7 += (c)*bhi((u).w);

#define RED2(v) { v += __shfl_xor(v, 16); v += __shfl_xor(v, 32); }

// ---------------- layer-0 aggregate fused with pair max-pool (8-deep gather ILP) --------
// lane = 16*g + l16; per iter lane-group g handles slots base+g+4j, j=0..7 (32 slots/wave)
__global__ __launch_bounds__(256) void mp0_kernel(
    const int* __restrict__ starts, const uint4* __restrict__ payload,
    const float* __restrict__ dis0, const unsigned* __restrict__ h0b, const float* __restrict__ origin,
    const float* __restrict__ We, const float* __restrict__ be, float* __restrict__ xp, int N2)
{
  int p = blockIdx.x*4 + (threadIdx.x >> 6);
  if (p >= N2) return;
  int lane = threadIdx.x & 63;
  int g = lane >> 4, l16 = lane & 15;
  float wself = be[0];
#pragma unroll
  for (int i=0;i<12;i++) wself += We[i];
  int s = starts[p], e = starts[p+1];
  float aA0=0,aA1=0,aA2=0,aA3=0,aA4=0,aA5=0,aA6=0,aA7=0;
  float aB0=0,aB1=0,aB2=0,aB3=0,aB4=0,aB5=0,aB6=0,aB7=0;
  for (int base = s; base < e; base += 32){
    int rv0,rv1,rv2,rv3,rv4,rv5,rv6,rv7;
    float cf0,cf1,cf2,cf3,cf4,cf5,cf6,cf7;
#define LD0(j, rv, cf) { int slot = base + g + 4*j; bool ok = slot < e; \
      int sc = ok ? slot : (e-1); uint4 pv = payload[sc]; \
      rv = (int)pv.x; cf = ok ? __builtin_bit_cast(float, pv.y) : 0.f; }
    LD0(0,rv0,cf0) LD0(1,rv1,cf1) LD0(2,rv2,cf2) LD0(3,rv3,cf3)
    LD0(4,rv4,cf4) LD0(5,rv5,cf5) LD0(6,rv6,cf6) LD0(7,rv7,cf7)
#undef LD0
    uint4 u0 = *(const uint4*)(h0b + (size_t)(rv0 & 0x7FFFFFFF)*64 + l16*4);
    uint4 u1 = *(const uint4*)(h0b + (size_t)(rv1 & 0x7FFFFFFF)*64 + l16*4);
    uint4 u2 = *(const uint4*)(h0b + (size_t)(rv2 & 0x7FFFFFFF)*64 + l16*4);
    uint4 u3 = *(const uint4*)(h0b + (size_t)(rv3 & 0x7FFFFFFF)*64 + l16*4);
    uint4 u4 = *(const uint4*)(h0b + (size_t)(rv4 & 0x7FFFFFFF)*64 + l16*4);
    uint4 u5 = *(const uint4*)(h0b + (size_t)(rv5 & 0x7FFFFFFF)*64 + l16*4);
    uint4 u6 = *(const uint4*)(h0b + (size_t)(rv6 & 0x7FFFFFFF)*64 + l16*4);
    uint4 u7 = *(const uint4*)(h0b + (size_t)(rv7 & 0x7FFFFFFF)*64 + l16*4);
#define ACCAB(u, rv, cf) { \
      float cB = ((rv) < 0) ? (cf) : 0.f; float cA = ((rv) < 0) ? 0.f : (cf); \
      ACC8(u, cA, aA0,aA1,aA2,aA3,aA4,aA5,aA6,aA7) \
      ACC8(u, cB, aB0,aB1,aB2,aB3,aB4,aB5,aB6,aB7) }
    ACCAB(u0,rv0,cf0) ACCAB(u1,rv1,cf1) ACCAB(u2,rv2,cf2) ACCAB(u3,rv3,cf3)
    ACCAB(u4,rv4,cf4) ACCAB(u5,rv5,cf5) ACCAB(u6,rv6,cf6) ACCAB(u7,rv7,cf7)
#undef ACCAB
  }
  RED2(aA0) RED2(aA1) RED2(aA2) RED2(aA3) RED2(aA4) RED2(aA5) RED2(aA6) RED2(aA7)
  RED2(aB0) RED2(aB1) RED2(aB2) RED2(aB3) RED2(aB4) RED2(aB5) RED2(aB6) RED2(aB7)
  float axA = (g==0)?aA0:(g==1)?aA2:(g==2)?aA4:aA6;
  float ayA = (g==0)?aA1:(g==1)?aA3:(g==2)?aA5:aA7;
  float axB = (g==0)?aB0:(g==1)?aB2:(g==2)?aB4:aB6;
  float ayB = (g==0)?aB1:(g==1)?aB3:(g==2)?aB5:aB7;
  int col2 = l16*8 + 2*g;
  int nA = 2*p, nB = 2*p+1;
  float dnA = dis0[nA], dnB = dis0[nB];
  unsigned uA = h0b[(size_t)nA*64 + (col2>>1)];
  unsigned uB = h0b[(size_t)nB*64 + (col2>>1)];
  const float2 ogA = *(const float2*)(origin + (size_t)nA*128 + col2);
  const float2 ogB = *(const float2*)(origin + (size_t)nB*128 + col2);
  float oxA = leakyf(dnA*(axA + wself*blo(uA)) + ogA.x);
  float oyA = leakyf(dnA*(ayA + wself*bhi(uA)) + ogA.y);
  float oxB = leakyf(dnB*(axB + wself*blo(uB)) + ogB.x);
  float oyB = leakyf(dnB*(ayB + wself*bhi(uB)) + ogB.y);
  float2 o2 = {fmaxf(oxA, oxB), fmaxf(oyA, oyB)};
  *(float2*)(xp + (size_t)p*128 + col2) = o2;
}

// ---------------- layer-1 aggregate + block-reduced global max pool (8-deep ILP) --------
__global__ __launch_bounds__(256) void mp1_kernel(
    const int* __restrict__ starts, const uint4* __restrict__ payload,
    const float* __restrict__ dis1, const unsigned* __restrict__ h1b,
    const float* __restrict__ We, const float* __restrict__ be,
    const int* __restrict__ batch_p, unsigned* __restrict__ genc, int N2)
{
  __shared__ unsigned lv[4][128];
  __shared__ int lb[4];
  int w = threadIdx.x >> 6;
  int n = blockIdx.x*4 + w;
  int lane = threadIdx.x & 63;
  int g = lane >> 4, l16 = lane & 15;
  bool valid = n < N2;
  float wself = be[0];
#pragma unroll
  for (int i=0;i<12;i++) wself += We[i];
  int s = 0, e = 0; float dn = 0.f;
  if (valid){ s = starts[n]; e = starts[n+1]; dn = dis1[n]; }
  float a0=0,a1=0,a2=0,a3=0,a4=0,a5=0,a6=0,a7=0;
  for (int base = s; base < e; base += 32){
    int rp0,rp1,rp2,rp3,rp4,rp5,rp6,rp7;
    float cf0,cf1,cf2,cf3,cf4,cf5,cf6,cf7;
#define LD1(j, rp, cf) { int slot = base + g + 4*j; bool ok = slot < e; \
      int sc = ok ? slot : (e-1); uint4 pv = payload[sc]; \
      rp = (int)(pv.x & 0x7FFFFFFF) >> 1; \
      cf = (ok && rp != n) ? __builtin_bit_cast(float, pv.z) : 0.f; }
    LD1(0,rp0,cf0) LD1(1,rp1,cf1) LD1(2,rp2,cf2) LD1(3,rp3,cf3)
    LD1(4,rp4,cf4) LD1(5,rp5,cf5) LD1(6,rp6,cf6) LD1(7,rp7,cf7)
#undef LD1
    uint4 u0 = *(const uint4*)(h1b + (size_t)rp0*64 + l16*4);
    uint4 u1 = *(const uint4*)(h1b + (size_t)rp1*64 + l16*4);
    uint4 u2 = *(const uint4*)(h1b + (size_t)rp2*64 + l16*4);
    uint4 u3 = *(const uint4*)(h1b + (size_t)rp3*64 + l16*4);
    uint4 u4 = *(const uint4*)(h1b + (size_t)rp4*64 + l16*4);
    uint4 u5 = *(const uint4*)(h1b + (size_t)rp5*64 + l16*4);
    uint4 u6 = *(const uint4*)(h1b + (size_t)rp6*64 + l16*4);
    uint4 u7 = *(const uint4*)(h1b + (size_t)rp7*64 + l16*4);
    ACC8(u0, cf0, a0,a1,a2,a3,a4,a5,a6,a7)
    ACC8(u1, cf1, a0,a1,a2,a3,a4,a5,a6,a7)
    ACC8(u2, cf2, a0,a1,a2,a3,a4,a5,a6,a7)
    ACC8(u3, cf3, a0,a1,a2,a3,a4,a5,a6,a7)
    ACC8(u4, cf4, a0,a1,a2,a3,a4,a5,a6,a7)
    ACC8(u5, cf5, a0,a1,a2,a3,a4,a5,a6,a7)
    ACC8(u6, cf6, a0,a1,a2,a3,a4,a5,a6,a7)
    ACC8(u7, cf7, a0,a1,a2,a3,a4,a5,a6,a7)
  }
  RED2(a0) RED2(a1) RED2(a2) RED2(a3) RED2(a4) RED2(a5) RED2(a6) RED2(a7)
  int col2 = l16*8 + 2*g;
  if (valid){
    float vx = (g==0)?a0:(g==1)?a2:(g==2)?a4:a6;
    float vy = (g==0)?a1:(g==1)?a3:(g==2)?a5:a7;
    unsigned us = h1b[(size_t)n*64 + (col2>>1)];
    float ox = leakyf(dn*(vx + wself*blo(us)));
    float oy = leakyf(dn*(vy + wself*bhi(us)));
    lv[w][col2]   = f32_ord(ox);
    lv[w][col2+1] = f32_ord(oy);
    if (lane == 0) lb[w] = batch_p[n];
  } else {
    if (lane == 0) lb[w] = -1;
  }
  __syncthreads();
  int tid = threadIdx.x;
  if (tid < 128){
    int col = tid;
    unsigned m0 = 0, m1 = 0;
    int b0 = -2, b1 = -2;
#pragma unroll
    for (int q = 0; q < 4; ++q){
      int bq = lb[q];
      if (bq < 0) continue;
      unsigned v = lv[q][col];
      if (b0 == -2 || bq == b0){ b0 = bq; m0 = max(m0, v); }
      else if (b1 == -2 || bq == b1){ b1 = bq; m1 = max(m1, v); }
      else atomicMax(&genc[(size_t)bq*128 + col], v);
    }
    if (b0 >= 0) atomicMax(&genc[(size_t)b0*128 + col], m0);
    if (b1 >= 0) atomicMax(&genc[(size_t)b1*128 + col], m1);
  }
}

// ---------------- head MLP: [64,128] -> [64,64] -> [64] --------------------------------
__global__ __launch_bounds__(256) void head_kernel(
    const unsigned* __restrict__ genc, const float* __restrict__ W1, const float* __restrict__ b1,
    const float* __restrict__ s, const float* __restrict__ t,
    const float* __restrict__ W2, const float* __restrict__ b2, float* __restrict__ out)
{
  __shared__ float g[64][128];
  __shared__ float hh[64][64];
  int tid = threadIdx.x;
  for (int i = tid; i < 64*128; i += 256){
    unsigned u = genc[i];
    unsigned bits = (u & 0x80000000u) ? (u & 0x7FFFFFFFu) : ~u;
    g[i>>7][i&127] = __builtin_bit_cast(float, bits);
  }
  __syncthreads();
  int c = tid & 63;
  int q0 = tid >> 6;
  float accv[16];
#pragma unroll
  for (int i=0;i<16;i++) accv[i] = 0.f;
  for (int k=0;k<128;k++){
    float wv = W1[k*64 + c];
#pragma unroll
    for (int i=0;i<16;i++) accv[i] += g[q0*16+i][k] * wv;
  }
  float sc = s[c], sh = t[c], bb = b1[c];
#pragma unroll
  for (int i=0;i<16;i++){
    float v = (accv[i] + bb)*sc + sh;
    hh[q0*16+i][c] = leakyf(v);
  }
  __syncthreads();
  if (tid < 64){
    float a = b2[0];
    for (int k=0;k<64;k++) a += hh[tid][k]*W2[k];
    out[tid] = a;
  }
}

extern "C" void kernel_launch(void* const* d_in, const int* in_sizes, int n_in,
                              void* d_out, int out_size, void* d_ws, size_t ws_size,
                              hipStream_t stream)
{
  const float* x      = (const float*)d_in[0];
  const float* origin = (const float*)d_in[1];
  const float* ea     = (const float*)d_in[2];
  const int*   ei     = (const int*)d_in[3];
  const int*   batchp = (const int*)d_in[5];
  const float* l0_W1 = (const float*)d_in[6];
  const float* l0_b1 = (const float*)d_in[7];
  const float* l0_s  = (const float*)d_in[8];
  const float* l0_t  = (const float*)d_in[9];
  const float* l0_W2 = (const float*)d_in[10];
  const float* l0_b2 = (const float*)d_in[11];
  const float* l0_We = (const float*)d_in[12];
  const float* l0_be = (const float*)d_in[13];
  const float* l1_W1 = (const float*)d_in[14];
  const float* l1_b1 = (const float*)d_in[15];
  const float* l1_s  = (const float*)d_in[16];
  const float* l1_t  = (const float*)d_in[17];
  const float* l1_W2 = (const float*)d_in[18];
  const float* l1_b2 = (const float*)d_in[19];
  const float* l1_We = (const float*)d_in[20];
  const float* l1_be = (const float*)d_in[21];
  const float* hd_W1 = (const float*)d_in[22];
  const float* hd_b1 = (const float*)d_in[23];
  const float* hd_s  = (const float*)d_in[24];
  const float* hd_t  = (const float*)d_in[25];
  const float* hd_W2 = (const float*)d_in[26];
  const float* hd_b2 = (const float*)d_in[27];

  const int N  = in_sizes[0] / 128;   // 50000
  const int E  = in_sizes[2] / 12;    // 800000
  const int N2 = in_sizes[5];         // 25000
  const int G  = out_size;            // 64
  const int NB = (N2 + 255) / 256;    // scan blocks over pair bins
  const int CS = (E + NCHK - 1) / NCHK;  // edges per chunk (128 chunks)

  char* ws = (char*)d_ws;
  size_t off = 0;
  auto alloc = [&](size_t b){ size_t o = off; off += (b + 255) & ~(size_t)255; return o; };
  size_t oA   = alloc((size_t)N*128*4);      // pre-GEMM: Hc32|RH16|CO|colTotal ; then hmid0/hmid1
  size_t oB   = alloc((size_t)N*128*4);      // [0,12.8M): h0b/h1b bf16 ; [12.8M,25.6M): xp f32
  size_t oPL  = alloc((size_t)E*16);         // AoS payload {rv, c0, c1, pad}
  size_t oRK  = alloc((size_t)E*2);
  size_t oST  = alloc((size_t)(N2+1)*4);
  size_t oBS  = alloc((size_t)NB*4);
  size_t zbytes = (size_t)N2*4 + (size_t)G*128*4;
  size_t oZ   = alloc(zbytes);               // intra | genc
  size_t oIN  = oZ;
  size_t oGE  = oIN + (size_t)N2*4;
  size_t oD0  = alloc((size_t)N*4);
  size_t oD1  = alloc((size_t)N2*4);
  size_t oWsp = alloc((size_t)(16384*2 + 16384*2 + 32768*2 + 32768*2)*2);

  float* regA   = (float*)(ws + oA);
  // chunked-histogram scratch lives inside oA (dead before first GEMM writes regA)
  size_t aoff = oA;
  auto suballoc = [&](size_t b){ size_t o = aoff; aoff += (b + 255) & ~(size_t)255; return o; };
  unsigned*       Hc32 = (unsigned*)      (ws + suballoc((size_t)NCHK*(N2/4)*4));
  unsigned short* RH16 = (unsigned short*)(ws + suballoc((size_t)NCHK*N2*2));
  unsigned short* CO   = (unsigned short*)(ws + suballoc((size_t)NCHK*N2*2));
  int*      colTotal   = (int*)           (ws + suballoc((size_t)N2*4));

  unsigned* h0b = (unsigned*)(ws + oB);                  // 50000x128 bf16 (as uints)
  unsigned* h1b = (unsigned*)(ws + oB);                  // 25000x128 bf16 (h0b dead)
  float* xp     = (float*)(ws + oB + (size_t)N2*128*4);  // 25000x128 f32
  uint4* payload= (uint4*)(ws + oPL);
  unsigned short* lrank = (unsigned short*)(ws + oRK);
  int*   starts = (int*)(ws + oST);
  int*   bsum   = (int*)(ws + oBS);
  unsigned* intra = (unsigned*)(ws + oIN);
  unsigned* genc= (unsigned*)(ws + oGE);
  float* dis0   = (float*)(ws + oD0);
  float* dis1   = (float*)(ws + oD1);
  short* l0W1h  = (short*)(ws + oWsp);
  short* l0W1l  = l0W1h + 16384;
  short* l0W2h  = l0W1l + 16384;
  short* l0W2l  = l0W2h + 16384;
  short* l1W1h  = l0W2l + 16384;
  short* l1W1l  = l1W1h + 32768;
  short* l1W2h  = l1W1l + 32768;
  short* l1W2l  = l1W2h + 32768;

  hipMemsetAsync(ws + oZ, 0, zbytes, stream);

  prep_w_kernel<<<64, 256, 0, stream>>>(l0_W1, l0W1h, l0W1l, 128, 128);
  prep_w_kernel<<<64, 256, 0, stream>>>(l0_W2, l0W2h, l0W2l, 128, 128);
  prep_w_kernel<<<128, 256, 0, stream>>>(l1_W1, l1W1h, l1W1l, 128, 256);
  prep_w_kernel<<<128, 256, 0, stream>>>(l1_W2, l1W2h, l1W2l, 256, 128);

  hist_kernel<<<NCHK, 512, 0, stream>>>(ei, lrank, Hc32, RH16, intra, E, CS, N2);
  co_scan_kernel<<<(N2/4+255)/256, 256, 0, stream>>>(Hc32, CO, colTotal, N2);
  dis_kernel<<<(N2+255)/256, 256, 0, stream>>>(RH16, intra, dis0, dis1, N2);
  scan_partial_kernel<<<NB, 256, 0, stream>>>(colTotal, bsum, N2);
  scan_bsums_kernel<<<1, 64, 0, stream>>>(bsum, NB);
  scan_final_kernel<<<NB, 256, 0, stream>>>(colTotal, bsum, starts, N2);
  fill_kernel<<<(E/2+255)/256, 256, 0, stream>>>(ei, ea, l0_We, l0_be, l1_We, l1_be,
                                                 starts, lrank, CO, payload, E, CS, N2);

  // MLP0: x -> hmid0(regA) -> h0b (bf16, dis0-folded)
  gemm_split<8><<<(N+63)/64, 256, 0, stream>>>(x, l0W1h, l0W1l, l0_b1, l0_s, l0_t, nullptr, regA, N, 128, 1);
  gemm_split<8><<<(N+63)/64, 256, 0, stream>>>(regA, l0W2h, l0W2l, l0_b2, nullptr, nullptr, dis0, h0b, N, 128, 6);
  // aggregate layer0 fused with pair pool -> xp
  mp0_kernel<<<(N2+3)/4, 256, 0, stream>>>(starts, payload, dis0, h0b, origin, l0_We, l0_be, xp, N2);
  // MLP1: xp -> hmid1(regA, 25000x256) -> h1b (bf16, dis1-folded)
  gemm_split<16><<<(N2+63)/64, 256, 0, stream>>>(xp, l1W1h, l1W1l, l1_b1, l1_s, l1_t, nullptr, regA, N2, 128, 1);
  gemm_split<8><<<(N2+63)/64, 256, 0, stream>>>(regA, l1W2h, l1W2l, l1_b2, nullptr, nullptr, dis1, h1b, N2, 256, 6);
  // aggregate layer1 + block-reduced global max pool
  mp1_kernel<<<(N2+3)/4, 256, 0, stream>>>(starts, payload, dis1, h1b, l1_We, l1_be, batchp, genc, N2);
  // head
  head_kernel<<<1, 256, 0, stream>>>(genc, hd_W1, hd_b1, hd_s, hd_t, hd_W2, hd_b2, (float*)d_out);
}

// Round 13
// 272.550 us; speedup vs baseline: 1.0403x; 1.0403x over previous
//
#include <hip/hip_runtime.h>

typedef __attribute__((ext_vector_type(4))) float f32x4;
typedef __attribute__((ext_vector_type(8))) short bf16x8;

#define NCH 25088   // static bins (>= N2=25000), multiple of 4
#define NCHK 128    // histogram chunks

__device__ __forceinline__ unsigned short f32_to_bf16_rne(float f){
  unsigned u = __builtin_bit_cast(unsigned, f);
  unsigned r = u + 0x7FFFu + ((u >> 16) & 1u);
  return (unsigned short)(r >> 16);
}
__device__ __forceinline__ float bf16_hi_to_f32(unsigned short h){
  unsigned u = ((unsigned)h) << 16;
  return __builtin_bit_cast(float, u);
}
__device__ __forceinline__ float blo(unsigned u){ return bf16_hi_to_f32((unsigned short)(u & 0xFFFF)); }
__device__ __forceinline__ float bhi(unsigned u){ return bf16_hi_to_f32((unsigned short)(u >> 16)); }
__device__ __forceinline__ float leakyf(float v){ return v > 0.f ? v : 0.01f*v; }
__device__ __forceinline__ unsigned f32_ord(float f){
  unsigned u = __builtin_bit_cast(unsigned, f);
  return (u & 0x80000000u) ? ~u : (u | 0x80000000u);
}

// ---------------- weight pre-split into MFMA B-fragment layout (hi/lo bf16) -------------
__global__ void prep_w_kernel(const float* __restrict__ W, short* __restrict__ Wh,
                              short* __restrict__ Wl, int K, int N)
{
  int total = K*N;
  int NF = N >> 4;
  for (int i = blockIdx.x*blockDim.x + threadIdx.x; i < total; i += gridDim.x*blockDim.x){
    int k = i / N, n = i % N;
    float w = W[i];
    unsigned short h = f32_to_bf16_rne(w);
    unsigned short l = f32_to_bf16_rne(w - bf16_hi_to_f32(h));
    int kb = k >> 5, kr = k & 31, cb = n >> 4;
    int lanei = ((kr >> 3) << 4) | (n & 15);
    size_t dst = (((size_t)(kb*NF + cb))*64 + lanei)*8 + (kr & 7);
    Wh[dst] = (short)h; Wl[dst] = (short)l;
  }
}

// ---------------- fused chunk histogram, u8-packed LDS (75KB), 512 thr, 128 chunks ------
__global__ __launch_bounds__(512) void hist_kernel(const int* __restrict__ ei,
                                                   unsigned short* __restrict__ lrank,
                                                   unsigned* __restrict__ Hc32,
                                                   unsigned short* __restrict__ RH16,
                                                   unsigned* __restrict__ intra,
                                                   int E, int CS, int N2)
{
  __shared__ unsigned ccnt[NCH/4];
  __shared__ unsigned rcnt[NCH/2];
  int tid = threadIdx.x;
  for (int i = tid; i < NCH/4; i += 512) ccnt[i] = 0;
  for (int i = tid; i < NCH/2; i += 512) rcnt[i] = 0;
  __syncthreads();
  int s = blockIdx.x*CS, eend = min(E, s + CS);
  for (int e = s + tid; e < eend; e += 512){
    int r = ei[e], c = ei[E+e];
    int rp = r >> 1;
    atomicAdd(&rcnt[rp>>1], 1u << (((rp & 1) << 4) + ((r & 1) << 3)));
    int cb = c >> 1;
    int sh = (cb & 3) << 3;
    unsigned old = atomicAdd(&ccnt[cb>>2], 1u << sh);
    lrank[e] = (unsigned short)((old >> sh) & 0xFFu);
    if (rp == cb) atomicAdd(&intra[rp], 1u);
  }
  __syncthreads();
  unsigned* hc = Hc32 + (size_t)blockIdx.x*(N2 >> 2);
  for (int i = tid; i < (N2 >> 2); i += 512) hc[i] = ccnt[i];
  unsigned* rh32 = (unsigned*)(RH16 + (size_t)blockIdx.x*N2);
  for (int i = tid; i < (N2 >> 1); i += 512) rh32[i] = rcnt[i];
}

// ---------------- per-bin chunk-offset prefix + bin totals (4 bins/thread) --------------
__global__ void co_scan_kernel(const unsigned* __restrict__ Hc32,
                               unsigned short* __restrict__ CO,
                               int* __restrict__ colTotal, int N2)
{
  int q = blockIdx.x*blockDim.x + threadIdx.x;   // bins 4q..4q+3
  if (q >= (N2 >> 2)) return;
  unsigned a0=0,a1=0,a2=0,a3=0;
  for (int ch = 0; ch < NCHK; ++ch){
    unsigned v = Hc32[(size_t)ch*(N2>>2) + q];
    ushort4 co = {(unsigned short)a0,(unsigned short)a1,(unsigned short)a2,(unsigned short)a3};
    *(ushort4*)(CO + (size_t)ch*N2 + 4*q) = co;
    a0 += v & 0xFFu; a1 += (v>>8) & 0xFFu; a2 += (v>>16) & 0xFFu; a3 += (v>>24) & 0xFFu;
  }
  int4 ct = {(int)a0,(int)a1,(int)a2,(int)a3};
  *(int4*)(colTotal + 4*q) = ct;
}

// ---------------- dis from chunked row histograms (u16 packed even8|odd8) ---------------
__global__ void dis_kernel(const unsigned short* __restrict__ RH16,
                           const unsigned* __restrict__ intra,
                           float* __restrict__ dis0, float* __restrict__ dis1, int N2)
{
  int p = blockIdx.x*blockDim.x + threadIdx.x;
  if (p >= N2) return;
  unsigned se = 0, so = 0;
  for (int ch = 0; ch < NCHK; ++ch){
    unsigned v = RH16[(size_t)ch*N2 + p];
    se += v & 0xFFu; so += (v >> 8) & 0xFFu;
  }
  float2 d0 = { rsqrtf((float)se + 1.0f), rsqrtf((float)so + 1.0f) };
  *(float2*)(dis0 + 2*p) = d0;
  dis1[p] = rsqrtf((float)(se + so - intra[p]) + 1.0f);
}

// ---------------- 3-pass parallel exclusive scan over colTotal -------------------------
__global__ void scan_partial_kernel(const int* __restrict__ cnt, int* __restrict__ bsum, int N)
{
  __shared__ int ws[4];
  int t = threadIdx.x, lane = t & 63, wv = t >> 6;
  int i = blockIdx.x*256 + t;
  int v = (i < N) ? cnt[i] : 0;
#pragma unroll
  for (int d = 1; d < 64; d <<= 1) v += __shfl_xor(v, d);
  if (lane == 0) ws[wv] = v;
  __syncthreads();
  if (t == 0) bsum[blockIdx.x] = ws[0]+ws[1]+ws[2]+ws[3];
}

__global__ void scan_bsums_kernel(int* __restrict__ bsum, int NB)
{
  int lane = threadIdx.x;  // 64 threads, 1 wave
  int carry = 0;
  for (int base = 0; base < NB; base += 64){
    int i = base + lane;
    int v = (i < NB) ? bsum[i] : 0;
    int x = v;
#pragma unroll
    for (int d = 1; d < 64; d <<= 1){
      int y = __shfl_up(x, d);
      if (lane >= d) x += y;
    }
    if (i < NB) bsum[i] = x - v + carry;   // exclusive
    carry += __shfl(x, 63);
  }
}

__global__ void scan_final_kernel(const int* __restrict__ cnt, const int* __restrict__ bsum,
                                  int* __restrict__ starts, int N)
{
  __shared__ int wsum[4];
  int t = threadIdx.x, lane = t & 63, wv = t >> 6;
  int i = blockIdx.x*256 + t;
  int v = (i < N) ? cnt[i] : 0;
  int x = v;
#pragma unroll
  for (int d = 1; d < 64; d <<= 1){
    int y = __shfl_up(x, d);
    if (lane >= d) x += y;
  }
  if (lane == 63) wsum[wv] = x;
  __syncthreads();
  int woff = 0;
#pragma unroll
  for (int j = 0; j < 4; j++) if (j < wv) woff += wsum[j];
  int base = bsum[blockIdx.x] + woff;
  if (i < N) starts[i+1] = base + x;
  if (blockIdx.x == 0 && t == 0) starts[0] = 0;
}

// ---------------- CSR fill: 2 edges/thread, one 16B AoS store per edge ------------------
__global__ void fill_kernel(const int* __restrict__ ei, const float* __restrict__ ea,
                            const float* __restrict__ We0, const float* __restrict__ be0,
                            const float* __restrict__ We1, const float* __restrict__ be1,
                            const int* __restrict__ starts,
                            const unsigned short* __restrict__ lrank,
                            const unsigned short* __restrict__ CO,
                            uint4* __restrict__ payload,
                            int E, int CS, int N2)
{
  float A0[12], A1[12];
#pragma unroll
  for (int i=0;i<12;i++){ A0[i]=We0[i]; A1[i]=We1[i]; }
  float b0 = be0[0], b1 = be1[0];
  int e0 = (blockIdx.x*blockDim.x + threadIdx.x)*2;
  if (e0 >= E) return;
  int e1 = e0 + 1;
  bool has1 = e1 < E;
  int ra = ei[e0], ca = ei[E+e0];
  int rb = has1 ? ei[e1] : 0, cb = has1 ? ei[E+e1] : 0;
  const f32x4* apa = (const f32x4*)(ea + (size_t)e0*12);
  const f32x4* apb = (const f32x4*)(ea + (size_t)e1*12);
  f32x4 va0 = apa[0], va1 = apa[1], va2 = apa[2];
  f32x4 vb0, vb1, vb2;
  if (has1){ vb0 = apb[0]; vb1 = apb[1]; vb2 = apb[2]; }
  float sa0 = b0, sa1 = b1, sb0 = b0, sb1 = b1;
#pragma unroll
  for (int j=0;j<4;j++){ sa0 += va0[j]*A0[j];   sa1 += va0[j]*A1[j]; }
#pragma unroll
  for (int j=0;j<4;j++){ sa0 += va1[j]*A0[4+j]; sa1 += va1[j]*A1[4+j]; }
#pragma unroll
  for (int j=0;j<4;j++){ sa0 += va2[j]*A0[8+j]; sa1 += va2[j]*A1[8+j]; }
  {
    int bin = ca >> 1, ch = e0 / CS;
    int pos = starts[bin] + (int)CO[(size_t)ch*N2 + bin] + (int)lrank[e0];
    uint4 pay = { (unsigned)(ra | ((ca & 1) << 31)),
                  __builtin_bit_cast(unsigned, sa0),
                  __builtin_bit_cast(unsigned, sa1), 0u };
    payload[pos] = pay;
  }
  if (has1){
#pragma unroll
    for (int j=0;j<4;j++){ sb0 += vb0[j]*A0[j];   sb1 += vb0[j]*A1[j]; }
#pragma unroll
    for (int j=0;j<4;j++){ sb0 += vb1[j]*A0[4+j]; sb1 += vb1[j]*A1[4+j]; }
#pragma unroll
    for (int j=0;j<4;j++){ sb0 += vb2[j]*A0[8+j]; sb1 += vb2[j]*A1[8+j]; }
    int bin = cb >> 1, ch = e1 / CS;
    int pos = starts[bin] + (int)CO[(size_t)ch*N2 + bin] + (int)lrank[e1];
    uint4 pay = { (unsigned)(rb | ((cb & 1) << 31)),
                  __builtin_bit_cast(unsigned, sb0),
                  __builtin_bit_cast(unsigned, sb1), 0u };
    payload[pos] = pay;
  }
}

// ---------------- split-bf16 MFMA GEMM: Y = epilogue(X @ W + b) -------------------------
// XBF16=0: X is f32, 3-MFMA hi/lo split.  XBF16=1: X is bf16 (ushort), 2 MFMAs.
// flags&1: y = leaky(y*scale + shift);  flags&2: store bf16;  flags&4: y *= rowscale[row]
template<int NF, int XBF16>
__global__ __launch_bounds__(256) void gemm_split(
    const void* __restrict__ Xv, const short* __restrict__ Wh, const short* __restrict__ Wl,
    const float* __restrict__ bias, const float* __restrict__ scale, const float* __restrict__ shift,
    const float* __restrict__ rowscale,
    void* __restrict__ Yv, int M, int K, int flags)
{
  const int Nn = NF*16;
  int w = threadIdx.x >> 6, lane = threadIdx.x & 63;
  int r0 = blockIdx.x*64 + w*16;
  int arow = r0 + (lane & 15);
  long arow_c = (arow < M) ? arow : (M-1);
  int kHi = (lane >> 4) << 3;
  f32x4 acc[NF];
#pragma unroll
  for (int i=0;i<NF;i++){
#pragma unroll
    for (int j=0;j<4;j++) acc[i][j] = 0.f;
  }
  int KB = K >> 5;
  const float* aprowF = (const float*)Xv + arow_c*(long)K + kHi;
  const unsigned short* aprowB = (const unsigned short*)Xv + arow_c*(long)K + kHi;
  for (int kb=0; kb<KB; ++kb){
    bf16x8 ah, al;
    if (XBF16){
      ah = *(const bf16x8*)(aprowB + kb*32);
    } else {
      const float* ap = aprowF + kb*32;
      f32x4 a0 = *(const f32x4*)ap;
      f32x4 a1 = *(const f32x4*)(ap+4);
#pragma unroll
      for (int j=0;j<8;j++){
        float f = (j<4) ? a0[j] : a1[j-4];
        unsigned short h = f32_to_bf16_rne(f);
        ah[j] = (short)h;
        al[j] = (short)f32_to_bf16_rne(f - bf16_hi_to_f32(h));
      }
    }
    const short* bp  = Wh + ((size_t)kb*NF*64 + lane)*8;
    const short* bpl = Wl + ((size_t)kb*NF*64 + lane)*8;
#pragma unroll
    for (int cb=0; cb<NF; ++cb){
      bf16x8 bh = *(const bf16x8*)(bp  + (size_t)cb*512);
      bf16x8 bl = *(const bf16x8*)(bpl + (size_t)cb*512);
      acc[cb] = __builtin_amdgcn_mfma_f32_16x16x32_bf16(ah, bh, acc[cb], 0,0,0);
      acc[cb] = __builtin_amdgcn_mfma_f32_16x16x32_bf16(ah, bl, acc[cb], 0,0,0);
      if (!XBF16)
        acc[cb] = __builtin_amdgcn_mfma_f32_16x16x32_bf16(al, bh, acc[cb], 0,0,0);
    }
  }
  int crow = r0 + ((lane >> 4) << 2);
  int ccol = lane & 15;
  float rw[4] = {1.f,1.f,1.f,1.f};
  if (flags & 4){
#pragma unroll
    for (int r=0;r<4;r++) if (crow + r < M) rw[r] = rowscale[crow + r];
  }
  float* Yf = (float*)Yv;
  unsigned short* Yb = (unsigned short*)Yv;
#pragma unroll
  for (int cb=0; cb<NF; ++cb){
    int c = cb*16 + ccol;
    float b = bias[c];
    float sc = 1.f, sh = 0.f;
    if (flags & 1){ sc = scale[c]; sh = shift[c]; }
#pragma unroll
    for (int r=0;r<4;r++){
      int row = crow + r;
      if (row < M){
        float v = acc[cb][r] + b;
        if (flags & 1){ v = v*sc + sh; v = leakyf(v); }
        if (flags & 4) v *= rw[r];
        if (flags & 2) Yb[(size_t)row*Nn + c] = f32_to_bf16_rne(v);
        else           Yf[(size_t)row*Nn + c] = v;
      }
    }
  }
}

// accumulate one uint4 (8 bf16 cols) into 8 named scalars with coefficient c
#define ACC8(u, c, a0,a1,a2,a3,a4,a5,a6,a7) \
  a0 += (c)*blo((u).x); a1 += (c)*bhi((u).x); \
  a2 += (c)*blo((u).y); a3 += (c)*bhi((u).y); \
  a4 += (c)*blo((u).z); a5 += (c)*bhi((u).z); \
  a6 += (c)*blo((u).w); a7 += (c)*bhi((u).w);

#define RED2(v) { v += __shfl_xor(v, 16); v += __shfl_xor(v, 32); }

// ---------------- layer-0 aggregate fused with pair max-pool (4-deep, R11) --------------
__global__ __launch_bounds__(256) void mp0_kernel(
    const int* __restrict__ starts, const uint4* __restrict__ payload,
    const float* __restrict__ dis0, const unsigned* __restrict__ h0b, const float* __restrict__ origin,
    const float* __restrict__ We, const float* __restrict__ be, float* __restrict__ xp, int N2)
{
  int p = blockIdx.x*4 + (threadIdx.x >> 6);
  if (p >= N2) return;
  int lane = threadIdx.x & 63;
  int g = lane >> 4, l16 = lane & 15;
  float wself = be[0];
#pragma unroll
  for (int i=0;i<12;i++) wself += We[i];
  int s = starts[p], e = starts[p+1];
  float aA0=0,aA1=0,aA2=0,aA3=0,aA4=0,aA5=0,aA6=0,aA7=0;
  float aB0=0,aB1=0,aB2=0,aB3=0,aB4=0,aB5=0,aB6=0,aB7=0;
  for (int base = s; base < e; base += 16){
    int rv0,rv1,rv2,rv3; float cf0,cf1,cf2,cf3;
#define LD0(j, rv, cf) { int slot = base + g + 4*j; bool ok = slot < e; \
      int sc = ok ? slot : (e-1); uint4 pv = payload[sc]; \
      rv = (int)pv.x; cf = ok ? __builtin_bit_cast(float, pv.y) : 0.f; }
    LD0(0,rv0,cf0) LD0(1,rv1,cf1) LD0(2,rv2,cf2) LD0(3,rv3,cf3)
#undef LD0
    uint4 u0 = *(const uint4*)(h0b + (size_t)(rv0 & 0x7FFFFFFF)*64 + l16*4);
    uint4 u1 = *(const uint4*)(h0b + (size_t)(rv1 & 0x7FFFFFFF)*64 + l16*4);
    uint4 u2 = *(const uint4*)(h0b + (size_t)(rv2 & 0x7FFFFFFF)*64 + l16*4);
    uint4 u3 = *(const uint4*)(h0b + (size_t)(rv3 & 0x7FFFFFFF)*64 + l16*4);
#define ACCAB(u, rv, cf) { \
      float cB = ((rv) < 0) ? (cf) : 0.f; float cA = ((rv) < 0) ? 0.f : (cf); \
      ACC8(u, cA, aA0,aA1,aA2,aA3,aA4,aA5,aA6,aA7) \
      ACC8(u, cB, aB0,aB1,aB2,aB3,aB4,aB5,aB6,aB7) }
    ACCAB(u0,rv0,cf0) ACCAB(u1,rv1,cf1) ACCAB(u2,rv2,cf2) ACCAB(u3,rv3,cf3)
#undef ACCAB
  }
  RED2(aA0) RED2(aA1) RED2(aA2) RED2(aA3) RED2(aA4) RED2(aA5) RED2(aA6) RED2(aA7)
  RED2(aB0) RED2(aB1) RED2(aB2) RED2(aB3) RED2(aB4) RED2(aB5) RED2(aB6) RED2(aB7)
  float axA = (g==0)?aA0:(g==1)?aA2:(g==2)?aA4:aA6;
  float ayA = (g==0)?aA1:(g==1)?aA3:(g==2)?aA5:aA7;
  float axB = (g==0)?aB0:(g==1)?aB2:(g==2)?aB4:aB6;
  float ayB = (g==0)?aB1:(g==1)?aB3:(g==2)?aB5:aB7;
  int col2 = l16*8 + 2*g;
  int nA = 2*p, nB = 2*p+1;
  float dnA = dis0[nA], dnB = dis0[nB];
  unsigned uA = h0b[(size_t)nA*64 + (col2>>1)];
  unsigned uB = h0b[(size_t)nB*64 + (col2>>1)];
  const float2 ogA = *(const float2*)(origin + (size_t)nA*128 + col2);
  const float2 ogB = *(const float2*)(origin + (size_t)nB*128 + col2);
  float oxA = leakyf(dnA*(axA + wself*blo(uA)) + ogA.x);
  float oyA = leakyf(dnA*(ayA + wself*bhi(uA)) + ogA.y);
  float oxB = leakyf(dnB*(axB + wself*blo(uB)) + ogB.x);
  float oyB = leakyf(dnB*(ayB + wself*bhi(uB)) + ogB.y);
  float2 o2 = {fmaxf(oxA, oxB), fmaxf(oyA, oyB)};
  *(float2*)(xp + (size_t)p*128 + col2) = o2;
}

// ---------------- layer-1 aggregate + block-reduced global max pool (4-deep, R11) -------
__global__ __launch_bounds__(256) void mp1_kernel(
    const int* __restrict__ starts, const uint4* __restrict__ payload,
    const float* __restrict__ dis1, const unsigned* __restrict__ h1b,
    const float* __restrict__ We, const float* __restrict__ be,
    const int* __restrict__ batch_p, unsigned* __restrict__ genc, int N2)
{
  __shared__ unsigned lv[4][128];
  __shared__ int lb[4];
  int w = threadIdx.x >> 6;
  int n = blockIdx.x*4 + w;
  int lane = threadIdx.x & 63;
  int g = lane >> 4, l16 = lane & 15;
  bool valid = n < N2;
  float wself = be[0];
#pragma unroll
  for (int i=0;i<12;i++) wself += We[i];
  int s = 0, e = 0; float dn = 0.f;
  if (valid){ s = starts[n]; e = starts[n+1]; dn = dis1[n]; }
  float a0=0,a1=0,a2=0,a3=0,a4=0,a5=0,a6=0,a7=0;
  for (int base = s; base < e; base += 16){
    int rp0,rp1,rp2,rp3; float cf0,cf1,cf2,cf3;
#define LD1(j, rp, cf) { int slot = base + g + 4*j; bool ok = slot < e; \
      int sc = ok ? slot : (e-1); uint4 pv = payload[sc]; \
      rp = (int)(pv.x & 0x7FFFFFFF) >> 1; \
      cf = (ok && rp != n) ? __builtin_bit_cast(float, pv.z) : 0.f; }
    LD1(0,rp0,cf0) LD1(1,rp1,cf1) LD1(2,rp2,cf2) LD1(3,rp3,cf3)
#undef LD1
    uint4 u0 = *(const uint4*)(h1b + (size_t)rp0*64 + l16*4);
    uint4 u1 = *(const uint4*)(h1b + (size_t)rp1*64 + l16*4);
    uint4 u2 = *(const uint4*)(h1b + (size_t)rp2*64 + l16*4);
    uint4 u3 = *(const uint4*)(h1b + (size_t)rp3*64 + l16*4);
    ACC8(u0, cf0, a0,a1,a2,a3,a4,a5,a6,a7)
    ACC8(u1, cf1, a0,a1,a2,a3,a4,a5,a6,a7)
    ACC8(u2, cf2, a0,a1,a2,a3,a4,a5,a6,a7)
    ACC8(u3, cf3, a0,a1,a2,a3,a4,a5,a6,a7)
  }
  RED2(a0) RED2(a1) RED2(a2) RED2(a3) RED2(a4) RED2(a5) RED2(a6) RED2(a7)
  int col2 = l16*8 + 2*g;
  if (valid){
    float vx = (g==0)?a0:(g==1)?a2:(g==2)?a4:a6;
    float vy = (g==0)?a1:(g==1)?a3:(g==2)?a5:a7;
    unsigned us = h1b[(size_t)n*64 + (col2>>1)];
    float ox = leakyf(dn*(vx + wself*blo(us)));
    float oy = leakyf(dn*(vy + wself*bhi(us)));
    lv[w][col2]   = f32_ord(ox);
    lv[w][col2+1] = f32_ord(oy);
    if (lane == 0) lb[w] = batch_p[n];
  } else {
    if (lane == 0) lb[w] = -1;
  }
  __syncthreads();
  int tid = threadIdx.x;
  if (tid < 128){
    int col = tid;
    unsigned m0 = 0, m1 = 0;
    int b0 = -2, b1 = -2;
#pragma unroll
    for (int q = 0; q < 4; ++q){
      int bq = lb[q];
      if (bq < 0) continue;
      unsigned v = lv[q][col];
      if (b0 == -2 || bq == b0){ b0 = bq; m0 = max(m0, v); }
      else if (b1 == -2 || bq == b1){ b1 = bq; m1 = max(m1, v); }
      else atomicMax(&genc[(size_t)bq*128 + col], v);
    }
    if (b0 >= 0) atomicMax(&genc[(size_t)b0*128 + col], m0);
    if (b1 >= 0) atomicMax(&genc[(size_t)b1*128 + col], m1);
  }
}

// ---------------- head MLP: [64,128] -> [64,64] -> [64] --------------------------------
__global__ __launch_bounds__(256) void head_kernel(
    const unsigned* __restrict__ genc, const float* __restrict__ W1, const float* __restrict__ b1,
    const float* __restrict__ s, const float* __restrict__ t,
    const float* __restrict__ W2, const float* __restrict__ b2, float* __restrict__ out)
{
  __shared__ float g[64][128];
  __shared__ float hh[64][64];
  int tid = threadIdx.x;
  for (int i = tid; i < 64*128; i += 256){
    unsigned u = genc[i];
    unsigned bits = (u & 0x80000000u) ? (u & 0x7FFFFFFFu) : ~u;
    g[i>>7][i&127] = __builtin_bit_cast(float, bits);
  }
  __syncthreads();
  int c = tid & 63;
  int q0 = tid >> 6;
  float accv[16];
#pragma unroll
  for (int i=0;i<16;i++) accv[i] = 0.f;
  for (int k=0;k<128;k++){
    float wv = W1[k*64 + c];
#pragma unroll
    for (int i=0;i<16;i++) accv[i] += g[q0*16+i][k] * wv;
  }
  float sc = s[c], sh = t[c], bb = b1[c];
#pragma unroll
  for (int i=0;i<16;i++){
    float v = (accv[i] + bb)*sc + sh;
    hh[q0*16+i][c] = leakyf(v);
  }
  __syncthreads();
  if (tid < 64){
    float a = b2[0];
    for (int k=0;k<64;k++) a += hh[tid][k]*W2[k];
    out[tid] = a;
  }
}

extern "C" void kernel_launch(void* const* d_in, const int* in_sizes, int n_in,
                              void* d_out, int out_size, void* d_ws, size_t ws_size,
                              hipStream_t stream)
{
  const float* x      = (const float*)d_in[0];
  const float* origin = (const float*)d_in[1];
  const float* ea     = (const float*)d_in[2];
  const int*   ei     = (const int*)d_in[3];
  const int*   batchp = (const int*)d_in[5];
  const float* l0_W1 = (const float*)d_in[6];
  const float* l0_b1 = (const float*)d_in[7];
  const float* l0_s  = (const float*)d_in[8];
  const float* l0_t  = (const float*)d_in[9];
  const float* l0_W2 = (const float*)d_in[10];
  const float* l0_b2 = (const float*)d_in[11];
  const float* l0_We = (const float*)d_in[12];
  const float* l0_be = (const float*)d_in[13];
  const float* l1_W1 = (const float*)d_in[14];
  const float* l1_b1 = (const float*)d_in[15];
  const float* l1_s  = (const float*)d_in[16];
  const float* l1_t  = (const float*)d_in[17];
  const float* l1_W2 = (const float*)d_in[18];
  const float* l1_b2 = (const float*)d_in[19];
  const float* l1_We = (const float*)d_in[20];
  const float* l1_be = (const float*)d_in[21];
  const float* hd_W1 = (const float*)d_in[22];
  const float* hd_b1 = (const float*)d_in[23];
  const float* hd_s  = (const float*)d_in[24];
  const float* hd_t  = (const float*)d_in[25];
  const float* hd_W2 = (const float*)d_in[26];
  const float* hd_b2 = (const float*)d_in[27];

  const int N  = in_sizes[0] / 128;   // 50000
  const int E  = in_sizes[2] / 12;    // 800000
  const int N2 = in_sizes[5];         // 25000
  const int G  = out_size;            // 64
  const int NB = (N2 + 255) / 256;    // scan blocks over pair bins
  const int CS = (E + NCHK - 1) / NCHK;  // edges per chunk (128 chunks)

  char* ws = (char*)d_ws;
  size_t off = 0;
  auto alloc = [&](size_t b){ size_t o = off; off += (b + 255) & ~(size_t)255; return o; };
  size_t oA   = alloc((size_t)N*128*4);      // pre-GEMM: Hc32|RH16|CO|colTotal ; then hmid (bf16)
  size_t oB   = alloc((size_t)N*128*4);      // [0,12.8M): h0b/h1b bf16 ; [12.8M,25.6M): xp f32
  size_t oPL  = alloc((size_t)E*16);         // AoS payload {rv, c0, c1, pad}
  size_t oRK  = alloc((size_t)E*2);
  size_t oST  = alloc((size_t)(N2+1)*4);
  size_t oBS  = alloc((size_t)NB*4);
  size_t zbytes = (size_t)N2*4 + (size_t)G*128*4;
  size_t oZ   = alloc(zbytes);               // intra | genc
  size_t oIN  = oZ;
  size_t oGE  = oIN + (size_t)N2*4;
  size_t oD0  = alloc((size_t)N*4);
  size_t oD1  = alloc((size_t)N2*4);
  size_t oWsp = alloc((size_t)(16384*2 + 16384*2 + 32768*2 + 32768*2)*2);

  // chunked-histogram scratch lives inside oA (dead before first GEMM writes hmid)
  size_t aoff = oA;
  auto suballoc = [&](size_t b){ size_t o = aoff; aoff += (b + 255) & ~(size_t)255; return o; };
  unsigned*       Hc32 = (unsigned*)      (ws + suballoc((size_t)NCHK*(N2/4)*4));
  unsigned short* RH16 = (unsigned short*)(ws + suballoc((size_t)NCHK*N2*2));
  unsigned short* CO   = (unsigned short*)(ws + suballoc((size_t)NCHK*N2*2));
  int*      colTotal   = (int*)           (ws + suballoc((size_t)N2*4));

  unsigned short* hmid = (unsigned short*)(ws + oA);     // 50000x128 or 25000x256 bf16
  unsigned* h0b = (unsigned*)(ws + oB);                  // 50000x128 bf16 (as uints)
  unsigned* h1b = (unsigned*)(ws + oB);                  // 25000x128 bf16 (h0b dead)
  float* xp     = (float*)(ws + oB + (size_t)N2*128*4);  // 25000x128 f32
  uint4* payload= (uint4*)(ws + oPL);
  unsigned short* lrank = (unsigned short*)(ws + oRK);
  int*   starts = (int*)(ws + oST);
  int*   bsum   = (int*)(ws + oBS);
  unsigned* intra = (unsigned*)(ws + oIN);
  unsigned* genc= (unsigned*)(ws + oGE);
  float* dis0   = (float*)(ws + oD0);
  float* dis1   = (float*)(ws + oD1);
  short* l0W1h  = (short*)(ws + oWsp);
  short* l0W1l  = l0W1h + 16384;
  short* l0W2h  = l0W1l + 16384;
  short* l0W2l  = l0W2h + 16384;
  short* l1W1h  = l0W2l + 16384;
  short* l1W1l  = l1W1h + 32768;
  short* l1W2h  = l1W1l + 32768;
  short* l1W2l  = l1W2h + 32768;

  hipMemsetAsync(ws + oZ, 0, zbytes, stream);

  prep_w_kernel<<<64, 256, 0, stream>>>(l0_W1, l0W1h, l0W1l, 128, 128);
  prep_w_kernel<<<64, 256, 0, stream>>>(l0_W2, l0W2h, l0W2l, 128, 128);
  prep_w_kernel<<<128, 256, 0, stream>>>(l1_W1, l1W1h, l1W1l, 128, 256);
  prep_w_kernel<<<128, 256, 0, stream>>>(l1_W2, l1W2h, l1W2l, 256, 128);

  hist_kernel<<<NCHK, 512, 0, stream>>>(ei, lrank, Hc32, RH16, intra, E, CS, N2);
  co_scan_kernel<<<(N2/4+255)/256, 256, 0, stream>>>(Hc32, CO, colTotal, N2);
  dis_kernel<<<(N2+255)/256, 256, 0, stream>>>(RH16, intra, dis0, dis1, N2);
  scan_partial_kernel<<<NB, 256, 0, stream>>>(colTotal, bsum, N2);
  scan_bsums_kernel<<<1, 64, 0, stream>>>(bsum, NB);
  scan_final_kernel<<<NB, 256, 0, stream>>>(colTotal, bsum, starts, N2);
  fill_kernel<<<(E/2+255)/256, 256, 0, stream>>>(ei, ea, l0_We, l0_be, l1_We, l1_be,
                                                 starts, lrank, CO, payload, E, CS, N2);

  // MLP0: x (f32) -> hmid bf16 -> h0b (bf16, dis0-folded)
  gemm_split<8,0><<<(N+63)/64, 256, 0, stream>>>(x, l0W1h, l0W1l, l0_b1, l0_s, l0_t, nullptr, hmid, N, 128, 3);
  gemm_split<8,1><<<(N+63)/64, 256, 0, stream>>>(hmid, l0W2h, l0W2l, l0_b2, nullptr, nullptr, dis0, h0b, N, 128, 6);
  // aggregate layer0 fused with pair pool -> xp
  mp0_kernel<<<(N2+3)/4, 256, 0, stream>>>(starts, payload, dis0, h0b, origin, l0_We, l0_be, xp, N2);
  // MLP1: xp (f32) -> hmid bf16 (25000x256) -> h1b (bf16, dis1-folded)
  gemm_split<16,0><<<(N2+63)/64, 256, 0, stream>>>(xp, l1W1h, l1W1l, l1_b1, l1_s, l1_t, nullptr, hmid, N2, 128, 3);
  gemm_split<8,1><<<(N2+63)/64, 256, 0, stream>>>(hmid, l1W2h, l1W2l, l1_b2, nullptr, nullptr, dis1, h1b, N2, 256, 6);
  // aggregate layer1 + block-reduced global max pool
  mp1_kernel<<<(N2+3)/4, 256, 0, stream>>>(starts, payload, dis1, h1b, l1_We, l1_be, batchp, genc, N2);
  // head
  head_kernel<<<1, 256, 0, stream>>>(genc, hd_W1, hd_b1, hd_s, hd_t, hd_W2, hd_b2, (float*)d_out);
}

// Round 14
// 265.941 us; speedup vs baseline: 1.0662x; 1.0249x over previous
//
#include <hip/hip_runtime.h>

typedef __attribute__((ext_vector_type(4))) float f32x4;
typedef __attribute__((ext_vector_type(8))) short bf16x8;

#define NCH 25088   // static bins (>= N2=25000), multiple of 4
#define NCHK 128    // histogram chunks

__device__ __forceinline__ unsigned short f32_to_bf16_rne(float f){
  unsigned u = __builtin_bit_cast(unsigned, f);
  unsigned r = u + 0x7FFFu + ((u >> 16) & 1u);
  return (unsigned short)(r >> 16);
}
__device__ __forceinline__ float bf16_hi_to_f32(unsigned short h){
  unsigned u = ((unsigned)h) << 16;
  return __builtin_bit_cast(float, u);
}
__device__ __forceinline__ float blo(unsigned u){ return bf16_hi_to_f32((unsigned short)(u & 0xFFFF)); }
__device__ __forceinline__ float bhi(unsigned u){ return bf16_hi_to_f32((unsigned short)(u >> 16)); }
__device__ __forceinline__ float leakyf(float v){ return v > 0.f ? v : 0.01f*v; }
__device__ __forceinline__ unsigned f32_ord(float f){
  unsigned u = __builtin_bit_cast(unsigned, f);
  return (u & 0x80000000u) ? ~u : (u | 0x80000000u);
}

// ---------------- merged weight pre-split (all 4 matrices, one launch) ------------------
// layout per matrix: dst[((kb*NF+cb)*64 + lane)*8 + (kr&7)]
__device__ __forceinline__ void prep_one(const float* W, short* Wh, short* Wl,
                                         int idx, int N)
{
  int NF = N >> 4;
  int k = idx / N, n = idx % N;
  float w = W[idx];
  unsigned short h = f32_to_bf16_rne(w);
  unsigned short l = f32_to_bf16_rne(w - bf16_hi_to_f32(h));
  int kb = k >> 5, kr = k & 31, cb = n >> 4;
  int lanei = ((kr >> 3) << 4) | (n & 15);
  size_t dst = (((size_t)(kb*NF + cb))*64 + lanei)*8 + (kr & 7);
  Wh[dst] = (short)h; Wl[dst] = (short)l;
}

__global__ void prep_all_kernel(const float* __restrict__ W0, const float* __restrict__ W1,
                                const float* __restrict__ W2, const float* __restrict__ W3,
                                short* __restrict__ o0h, short* __restrict__ o0l,
                                short* __restrict__ o1h, short* __restrict__ o1l,
                                short* __restrict__ o2h, short* __restrict__ o2l,
                                short* __restrict__ o3h, short* __restrict__ o3l)
{
  // sizes: 16384 | 16384 | 32768 | 32768  (total 98304)
  for (int i = blockIdx.x*blockDim.x + threadIdx.x; i < 98304; i += gridDim.x*blockDim.x){
    if (i < 16384)       prep_one(W0, o0h, o0l, i, 128);
    else if (i < 32768)  prep_one(W1, o1h, o1l, i - 16384, 128);
    else if (i < 65536)  prep_one(W2, o2h, o2l, i - 32768, 256);
    else                 prep_one(W3, o3h, o3l, i - 65536, 128);
  }
}

// ---------------- fused chunk histogram, u8-packed LDS (75KB), 512 thr, 128 chunks ------
__global__ __launch_bounds__(512) void hist_kernel(const int* __restrict__ ei,
                                                   unsigned short* __restrict__ lrank,
                                                   unsigned* __restrict__ Hc32,
                                                   unsigned short* __restrict__ RH16,
                                                   unsigned* __restrict__ intra,
                                                   int E, int CS, int N2)
{
  __shared__ unsigned ccnt[NCH/4];
  __shared__ unsigned rcnt[NCH/2];
  int tid = threadIdx.x;
  for (int i = tid; i < NCH/4; i += 512) ccnt[i] = 0;
  for (int i = tid; i < NCH/2; i += 512) rcnt[i] = 0;
  __syncthreads();
  int s = blockIdx.x*CS, eend = min(E, s + CS);
  for (int e = s + tid; e < eend; e += 512){
    int r = ei[e], c = ei[E+e];
    int rp = r >> 1;
    atomicAdd(&rcnt[rp>>1], 1u << (((rp & 1) << 4) + ((r & 1) << 3)));
    int cb = c >> 1;
    int sh = (cb & 3) << 3;
    unsigned old = atomicAdd(&ccnt[cb>>2], 1u << sh);
    lrank[e] = (unsigned short)((old >> sh) & 0xFFu);
    if (rp == cb) atomicAdd(&intra[rp], 1u);
  }
  __syncthreads();
  unsigned* hc = Hc32 + (size_t)blockIdx.x*(N2 >> 2);
  for (int i = tid; i < (N2 >> 2); i += 512) hc[i] = ccnt[i];
  unsigned* rh32 = (unsigned*)(RH16 + (size_t)blockIdx.x*N2);
  for (int i = tid; i < (N2 >> 1); i += 512) rh32[i] = rcnt[i];
}

// ---------------- per-bin chunk-offset prefix + bin totals (4 bins/thread) --------------
__global__ void co_scan_kernel(const unsigned* __restrict__ Hc32,
                               unsigned short* __restrict__ CO,
                               int* __restrict__ colTotal, int N2)
{
  int q = blockIdx.x*blockDim.x + threadIdx.x;   // bins 4q..4q+3
  if (q >= (N2 >> 2)) return;
  unsigned a0=0,a1=0,a2=0,a3=0;
  for (int ch = 0; ch < NCHK; ++ch){
    unsigned v = Hc32[(size_t)ch*(N2>>2) + q];
    ushort4 co = {(unsigned short)a0,(unsigned short)a1,(unsigned short)a2,(unsigned short)a3};
    *(ushort4*)(CO + (size_t)ch*N2 + 4*q) = co;
    a0 += v & 0xFFu; a1 += (v>>8) & 0xFFu; a2 += (v>>16) & 0xFFu; a3 += (v>>24) & 0xFFu;
  }
  int4 ct = {(int)a0,(int)a1,(int)a2,(int)a3};
  *(int4*)(colTotal + 4*q) = ct;
}

// ---------------- dis from chunked row histograms (u16 packed even8|odd8) ---------------
__global__ void dis_kernel(const unsigned short* __restrict__ RH16,
                           const unsigned* __restrict__ intra,
                           float* __restrict__ dis0, float* __restrict__ dis1, int N2)
{
  int p = blockIdx.x*blockDim.x + threadIdx.x;
  if (p >= N2) return;
  unsigned se = 0, so = 0;
  for (int ch = 0; ch < NCHK; ++ch){
    unsigned v = RH16[(size_t)ch*N2 + p];
    se += v & 0xFFu; so += (v >> 8) & 0xFFu;
  }
  float2 d0 = { rsqrtf((float)se + 1.0f), rsqrtf((float)so + 1.0f) };
  *(float2*)(dis0 + 2*p) = d0;
  dis1[p] = rsqrtf((float)(se + so - intra[p]) + 1.0f);
}

// ---------------- 3-pass parallel exclusive scan over colTotal -------------------------
__global__ void scan_partial_kernel(const int* __restrict__ cnt, int* __restrict__ bsum, int N)
{
  __shared__ int ws[4];
  int t = threadIdx.x, lane = t & 63, wv = t >> 6;
  int i = blockIdx.x*256 + t;
  int v = (i < N) ? cnt[i] : 0;
#pragma unroll
  for (int d = 1; d < 64; d <<= 1) v += __shfl_xor(v, d);
  if (lane == 0) ws[wv] = v;
  __syncthreads();
  if (t == 0) bsum[blockIdx.x] = ws[0]+ws[1]+ws[2]+ws[3];
}

__global__ void scan_bsums_kernel(int* __restrict__ bsum, int NB)
{
  int lane = threadIdx.x;  // 64 threads, 1 wave
  int carry = 0;
  for (int base = 0; base < NB; base += 64){
    int i = base + lane;
    int v = (i < NB) ? bsum[i] : 0;
    int x = v;
#pragma unroll
    for (int d = 1; d < 64; d <<= 1){
      int y = __shfl_up(x, d);
      if (lane >= d) x += y;
    }
    if (i < NB) bsum[i] = x - v + carry;   // exclusive
    carry += __shfl(x, 63);
  }
}

__global__ void scan_final_kernel(const int* __restrict__ cnt, const int* __restrict__ bsum,
                                  int* __restrict__ starts, int N)
{
  __shared__ int wsum[4];
  int t = threadIdx.x, lane = t & 63, wv = t >> 6;
  int i = blockIdx.x*256 + t;
  int v = (i < N) ? cnt[i] : 0;
  int x = v;
#pragma unroll
  for (int d = 1; d < 64; d <<= 1){
    int y = __shfl_up(x, d);
    if (lane >= d) x += y;
  }
  if (lane == 63) wsum[wv] = x;
  __syncthreads();
  int woff = 0;
#pragma unroll
  for (int j = 0; j < 4; j++) if (j < wv) woff += wsum[j];
  int base = bsum[blockIdx.x] + woff;
  if (i < N) starts[i+1] = base + x;
  if (blockIdx.x == 0 && t == 0) starts[0] = 0;
}

// ---------------- CSR fill: 1 edge/thread, one 16B AoS store per edge -------------------
__global__ void fill_kernel(const int* __restrict__ ei, const float* __restrict__ ea,
                            const float* __restrict__ We0, const float* __restrict__ be0,
                            const float* __restrict__ We1, const float* __restrict__ be1,
                            const int* __restrict__ starts,
                            const unsigned short* __restrict__ lrank,
                            const unsigned short* __restrict__ CO,
                            uint4* __restrict__ payload,
                            int E, int CS, int N2)
{
  float A0[12], A1[12];
#pragma unroll
  for (int i=0;i<12;i++){ A0[i]=We0[i]; A1[i]=We1[i]; }
  float b0 = be0[0], b1 = be1[0];
  int e = blockIdx.x*blockDim.x + threadIdx.x;
  if (e >= E) return;
  int r = ei[e], c = ei[E+e];
  const f32x4* ap = (const f32x4*)(ea + (size_t)e*12);
  f32x4 v0 = ap[0], v1 = ap[1], v2 = ap[2];
  float s0 = b0, s1 = b1;
#pragma unroll
  for (int j=0;j<4;j++){ s0 += v0[j]*A0[j];   s1 += v0[j]*A1[j]; }
#pragma unroll
  for (int j=0;j<4;j++){ s0 += v1[j]*A0[4+j]; s1 += v1[j]*A1[4+j]; }
#pragma unroll
  for (int j=0;j<4;j++){ s0 += v2[j]*A0[8+j]; s1 += v2[j]*A1[8+j]; }
  int bin = c >> 1;
  int ch  = e / CS;
  int pos = starts[bin] + (int)CO[(size_t)ch*N2 + bin] + (int)lrank[e];
  uint4 pay;
  pay.x = (unsigned)(r | ((c & 1) << 31));
  pay.y = __builtin_bit_cast(unsigned, s0);
  pay.z = __builtin_bit_cast(unsigned, s1);
  pay.w = 0u;
  payload[pos] = pay;
}

// ---------------- split-bf16 MFMA GEMM: Y = epilogue(X @ W + b) -------------------------
// XBF16=0: X is f32, 3-MFMA hi/lo split.  XBF16=1: X is bf16 (ushort), 2 MFMAs.
// flags&1: y = leaky(y*scale + shift);  flags&2: store bf16;  flags&4: y *= rowscale[row]
template<int NF, int XBF16>
__global__ __launch_bounds__(256) void gemm_split(
    const void* __restrict__ Xv, const short* __restrict__ Wh, const short* __restrict__ Wl,
    const float* __restrict__ bias, const float* __restrict__ scale, const float* __restrict__ shift,
    const float* __restrict__ rowscale,
    void* __restrict__ Yv, int M, int K, int flags)
{
  const int Nn = NF*16;
  int w = threadIdx.x >> 6, lane = threadIdx.x & 63;
  int r0 = blockIdx.x*64 + w*16;
  int arow = r0 + (lane & 15);
  long arow_c = (arow < M) ? arow : (M-1);
  int kHi = (lane >> 4) << 3;
  f32x4 acc[NF];
#pragma unroll
  for (int i=0;i<NF;i++){
#pragma unroll
    for (int j=0;j<4;j++) acc[i][j] = 0.f;
  }
  int KB = K >> 5;
  const float* aprowF = (const float*)Xv + arow_c*(long)K + kHi;
  const unsigned short* aprowB = (const unsigned short*)Xv + arow_c*(long)K + kHi;
  for (int kb=0; kb<KB; ++kb){
    bf16x8 ah, al;
    if (XBF16){
      ah = *(const bf16x8*)(aprowB + kb*32);
    } else {
      const float* ap = aprowF + kb*32;
      f32x4 a0 = *(const f32x4*)ap;
      f32x4 a1 = *(const f32x4*)(ap+4);
#pragma unroll
      for (int j=0;j<8;j++){
        float f = (j<4) ? a0[j] : a1[j-4];
        unsigned short h = f32_to_bf16_rne(f);
        ah[j] = (short)h;
        al[j] = (short)f32_to_bf16_rne(f - bf16_hi_to_f32(h));
      }
    }
    const short* bp  = Wh + ((size_t)kb*NF*64 + lane)*8;
    const short* bpl = Wl + ((size_t)kb*NF*64 + lane)*8;
#pragma unroll
    for (int cb=0; cb<NF; ++cb){
      bf16x8 bh = *(const bf16x8*)(bp  + (size_t)cb*512);
      bf16x8 bl = *(const bf16x8*)(bpl + (size_t)cb*512);
      acc[cb] = __builtin_amdgcn_mfma_f32_16x16x32_bf16(ah, bh, acc[cb], 0,0,0);
      acc[cb] = __builtin_amdgcn_mfma_f32_16x16x32_bf16(ah, bl, acc[cb], 0,0,0);
      if (!XBF16)
        acc[cb] = __builtin_amdgcn_mfma_f32_16x16x32_bf16(al, bh, acc[cb], 0,0,0);
    }
  }
  int crow = r0 + ((lane >> 4) << 2);
  int ccol = lane & 15;
  float rw[4] = {1.f,1.f,1.f,1.f};
  if (flags & 4){
#pragma unroll
    for (int r=0;r<4;r++) if (crow + r < M) rw[r] = rowscale[crow + r];
  }
  float* Yf = (float*)Yv;
  unsigned short* Yb = (unsigned short*)Yv;
#pragma unroll
  for (int cb=0; cb<NF; ++cb){
    int c = cb*16 + ccol;
    float b = bias[c];
    float sc = 1.f, sh = 0.f;
    if (flags & 1){ sc = scale[c]; sh = shift[c]; }
#pragma unroll
    for (int r=0;r<4;r++){
      int row = crow + r;
      if (row < M){
        float v = acc[cb][r] + b;
        if (flags & 1){ v = v*sc + sh; v = leakyf(v); }
        if (flags & 4) v *= rw[r];
        if (flags & 2) Yb[(size_t)row*Nn + c] = f32_to_bf16_rne(v);
        else           Yf[(size_t)row*Nn + c] = v;
      }
    }
  }
}

// accumulate one uint4 (8 bf16 cols) into 8 named scalars with coefficient c
#define ACC8(u, c, a0,a1,a2,a3,a4,a5,a6,a7) \
  a0 += (c)*blo((u).x); a1 += (c)*bhi((u).x); \
  a2 += (c)*blo((u).y); a3 += (c)*bhi((u).y); \
  a4 += (c)*blo((u).z); a5 += (c)*bhi((u).z); \
  a6 += (c)*blo((u).w); a7 += (c)*bhi((u).w);

#define RED2(v) { v += __shfl_xor(v, 16); v += __shfl_xor(v, 32); }

// ---------------- layer-0 aggregate fused with pair max-pool (4-deep) -------------------
__global__ __launch_bounds__(256) void mp0_kernel(
    const int* __restrict__ starts, const uint4* __restrict__ payload,
    const float* __restrict__ dis0, const unsigned* __restrict__ h0b, const float* __restrict__ origin,
    const float* __restrict__ We, const float* __restrict__ be, float* __restrict__ xp, int N2)
{
  int p = blockIdx.x*4 + (threadIdx.x >> 6);
  if (p >= N2) return;
  int lane = threadIdx.x & 63;
  int g = lane >> 4, l16 = lane & 15;
  float wself = be[0];
#pragma unroll
  for (int i=0;i<12;i++) wself += We[i];
  int s = starts[p], e = starts[p+1];
  float aA0=0,aA1=0,aA2=0,aA3=0,aA4=0,aA5=0,aA6=0,aA7=0;
  float aB0=0,aB1=0,aB2=0,aB3=0,aB4=0,aB5=0,aB6=0,aB7=0;
  for (int base = s; base < e; base += 16){
    int rv0,rv1,rv2,rv3; float cf0,cf1,cf2,cf3;
#define LD0(j, rv, cf) { int slot = base + g + 4*j; bool ok = slot < e; \
      int sc = ok ? slot : (e-1); uint4 pv = payload[sc]; \
      rv = (int)pv.x; cf = ok ? __builtin_bit_cast(float, pv.y) : 0.f; }
    LD0(0,rv0,cf0) LD0(1,rv1,cf1) LD0(2,rv2,cf2) LD0(3,rv3,cf3)
#undef LD0
    uint4 u0 = *(const uint4*)(h0b + (size_t)(rv0 & 0x7FFFFFFF)*64 + l16*4);
    uint4 u1 = *(const uint4*)(h0b + (size_t)(rv1 & 0x7FFFFFFF)*64 + l16*4);
    uint4 u2 = *(const uint4*)(h0b + (size_t)(rv2 & 0x7FFFFFFF)*64 + l16*4);
    uint4 u3 = *(const uint4*)(h0b + (size_t)(rv3 & 0x7FFFFFFF)*64 + l16*4);
#define ACCAB(u, rv, cf) { \
      float cB = ((rv) < 0) ? (cf) : 0.f; float cA = ((rv) < 0) ? 0.f : (cf); \
      ACC8(u, cA, aA0,aA1,aA2,aA3,aA4,aA5,aA6,aA7) \
      ACC8(u, cB, aB0,aB1,aB2,aB3,aB4,aB5,aB6,aB7) }
    ACCAB(u0,rv0,cf0) ACCAB(u1,rv1,cf1) ACCAB(u2,rv2,cf2) ACCAB(u3,rv3,cf3)
#undef ACCAB
  }
  RED2(aA0) RED2(aA1) RED2(aA2) RED2(aA3) RED2(aA4) RED2(aA5) RED2(aA6) RED2(aA7)
  RED2(aB0) RED2(aB1) RED2(aB2) RED2(aB3) RED2(aB4) RED2(aB5) RED2(aB6) RED2(aB7)
  float axA = (g==0)?aA0:(g==1)?aA2:(g==2)?aA4:aA6;
  float ayA = (g==0)?aA1:(g==1)?aA3:(g==2)?aA5:aA7;
  float axB = (g==0)?aB0:(g==1)?aB2:(g==2)?aB4:aB6;
  float ayB = (g==0)?aB1:(g==1)?aB3:(g==2)?aB5:aB7;
  int col2 = l16*8 + 2*g;
  int nA = 2*p, nB = 2*p+1;
  float dnA = dis0[nA], dnB = dis0[nB];
  unsigned uA = h0b[(size_t)nA*64 + (col2>>1)];
  unsigned uB = h0b[(size_t)nB*64 + (col2>>1)];
  const float2 ogA = *(const float2*)(origin + (size_t)nA*128 + col2);
  const float2 ogB = *(const float2*)(origin + (size_t)nB*128 + col2);
  float oxA = leakyf(dnA*(axA + wself*blo(uA)) + ogA.x);
  float oyA = leakyf(dnA*(ayA + wself*bhi(uA)) + ogA.y);
  float oxB = leakyf(dnB*(axB + wself*blo(uB)) + ogB.x);
  float oyB = leakyf(dnB*(ayB + wself*bhi(uB)) + ogB.y);
  float2 o2 = {fmaxf(oxA, oxB), fmaxf(oyA, oyB)};
  *(float2*)(xp + (size_t)p*128 + col2) = o2;
}

// ---------------- layer-1 aggregate + block-reduced global max pool (4-deep) ------------
__global__ __launch_bounds__(256) void mp1_kernel(
    const int* __restrict__ starts, const uint4* __restrict__ payload,
    const float* __restrict__ dis1, const unsigned* __restrict__ h1b,
    const float* __restrict__ We, const float* __restrict__ be,
    const int* __restrict__ batch_p, unsigned* __restrict__ genc, int N2)
{
  __shared__ unsigned lv[4][128];
  __shared__ int lb[4];
  int w = threadIdx.x >> 6;
  int n = blockIdx.x*4 + w;
  int lane = threadIdx.x & 63;
  int g = lane >> 4, l16 = lane & 15;
  bool valid = n < N2;
  float wself = be[0];
#pragma unroll
  for (int i=0;i<12;i++) wself += We[i];
  int s = 0, e = 0; float dn = 0.f;
  if (valid){ s = starts[n]; e = starts[n+1]; dn = dis1[n]; }
  float a0=0,a1=0,a2=0,a3=0,a4=0,a5=0,a6=0,a7=0;
  for (int base = s; base < e; base += 16){
    int rp0,rp1,rp2,rp3; float cf0,cf1,cf2,cf3;
#define LD1(j, rp, cf) { int slot = base + g + 4*j; bool ok = slot < e; \
      int sc = ok ? slot : (e-1); uint4 pv = payload[sc]; \
      rp = (int)(pv.x & 0x7FFFFFFF) >> 1; \
      cf = (ok && rp != n) ? __builtin_bit_cast(float, pv.z) : 0.f; }
    LD1(0,rp0,cf0) LD1(1,rp1,cf1) LD1(2,rp2,cf2) LD1(3,rp3,cf3)
#undef LD1
    uint4 u0 = *(const uint4*)(h1b + (size_t)rp0*64 + l16*4);
    uint4 u1 = *(const uint4*)(h1b + (size_t)rp1*64 + l16*4);
    uint4 u2 = *(const uint4*)(h1b + (size_t)rp2*64 + l16*4);
    uint4 u3 = *(const uint4*)(h1b + (size_t)rp3*64 + l16*4);
    ACC8(u0, cf0, a0,a1,a2,a3,a4,a5,a6,a7)
    ACC8(u1, cf1, a0,a1,a2,a3,a4,a5,a6,a7)
    ACC8(u2, cf2, a0,a1,a2,a3,a4,a5,a6,a7)
    ACC8(u3, cf3, a0,a1,a2,a3,a4,a5,a6,a7)
  }
  RED2(a0) RED2(a1) RED2(a2) RED2(a3) RED2(a4) RED2(a5) RED2(a6) RED2(a7)
  int col2 = l16*8 + 2*g;
  if (valid){
    float vx = (g==0)?a0:(g==1)?a2:(g==2)?a4:a6;
    float vy = (g==0)?a1:(g==1)?a3:(g==2)?a5:a7;
    unsigned us = h1b[(size_t)n*64 + (col2>>1)];
    float ox = leakyf(dn*(vx + wself*blo(us)));
    float oy = leakyf(dn*(vy + wself*bhi(us)));
    lv[w][col2]   = f32_ord(ox);
    lv[w][col2+1] = f32_ord(oy);
    if (lane == 0) lb[w] = batch_p[n];
  } else {
    if (lane == 0) lb[w] = -1;
  }
  __syncthreads();
  int tid = threadIdx.x;
  if (tid < 128){
    int col = tid;
    unsigned m0 = 0, m1 = 0;
    int b0 = -2, b1 = -2;
#pragma unroll
    for (int q = 0; q < 4; ++q){
      int bq = lb[q];
      if (bq < 0) continue;
      unsigned v = lv[q][col];
      if (b0 == -2 || bq == b0){ b0 = bq; m0 = max(m0, v); }
      else if (b1 == -2 || bq == b1){ b1 = bq; m1 = max(m1, v); }
      else atomicMax(&genc[(size_t)bq*128 + col], v);
    }
    if (b0 >= 0) atomicMax(&genc[(size_t)b0*128 + col], m0);
    if (b1 >= 0) atomicMax(&genc[(size_t)b1*128 + col], m1);
  }
}

// ---------------- head MLP: [64,128] -> [64,64] -> [64] --------------------------------
__global__ __launch_bounds__(256) void head_kernel(
    const unsigned* __restrict__ genc, const float* __restrict__ W1, const float* __restrict__ b1,
    const float* __restrict__ s, const float* __restrict__ t,
    const float* __restrict__ W2, const float* __restrict__ b2, float* __restrict__ out)
{
  __shared__ float g[64][128];
  __shared__ float hh[64][64];
  int tid = threadIdx.x;
  for (int i = tid; i < 64*128; i += 256){
    unsigned u = genc[i];
    unsigned bits = (u & 0x80000000u) ? (u & 0x7FFFFFFFu) : ~u;
    g[i>>7][i&127] = __builtin_bit_cast(float, bits);
  }
  __syncthreads();
  int c = tid & 63;
  int q0 = tid >> 6;
  float accv[16];
#pragma unroll
  for (int i=0;i<16;i++) accv[i] = 0.f;
  for (int k=0;k<128;k++){
    float wv = W1[k*64 + c];
#pragma unroll
    for (int i=0;i<16;i++) accv[i] += g[q0*16+i][k] * wv;
  }
  float sc = s[c], sh = t[c], bb = b1[c];
#pragma unroll
  for (int i=0;i<16;i++){
    float v = (accv[i] + bb)*sc + sh;
    hh[q0*16+i][c] = leakyf(v);
  }
  __syncthreads();
  if (tid < 64){
    float a = b2[0];
    for (int k=0;k<64;k++) a += hh[tid][k]*W2[k];
    out[tid] = a;
  }
}

extern "C" void kernel_launch(void* const* d_in, const int* in_sizes, int n_in,
                              void* d_out, int out_size, void* d_ws, size_t ws_size,
                              hipStream_t stream)
{
  const float* x      = (const float*)d_in[0];
  const float* origin = (const float*)d_in[1];
  const float* ea     = (const float*)d_in[2];
  const int*   ei     = (const int*)d_in[3];
  const int*   batchp = (const int*)d_in[5];
  const float* l0_W1 = (const float*)d_in[6];
  const float* l0_b1 = (const float*)d_in[7];
  const float* l0_s  = (const float*)d_in[8];
  const float* l0_t  = (const float*)d_in[9];
  const float* l0_W2 = (const float*)d_in[10];
  const float* l0_b2 = (const float*)d_in[11];
  const float* l0_We = (const float*)d_in[12];
  const float* l0_be = (const float*)d_in[13];
  const float* l1_W1 = (const float*)d_in[14];
  const float* l1_b1 = (const float*)d_in[15];
  const float* l1_s  = (const float*)d_in[16];
  const float* l1_t  = (const float*)d_in[17];
  const float* l1_W2 = (const float*)d_in[18];
  const float* l1_b2 = (const float*)d_in[19];
  const float* l1_We = (const float*)d_in[20];
  const float* l1_be = (const float*)d_in[21];
  const float* hd_W1 = (const float*)d_in[22];
  const float* hd_b1 = (const float*)d_in[23];
  const float* hd_s  = (const float*)d_in[24];
  const float* hd_t  = (const float*)d_in[25];
  const float* hd_W2 = (const float*)d_in[26];
  const float* hd_b2 = (const float*)d_in[27];

  const int N  = in_sizes[0] / 128;   // 50000
  const int E  = in_sizes[2] / 12;    // 800000
  const int N2 = in_sizes[5];         // 25000
  const int G  = out_size;            // 64
  const int NB = (N2 + 255) / 256;    // scan blocks over pair bins
  const int CS = (E + NCHK - 1) / NCHK;  // edges per chunk (128 chunks)

  char* ws = (char*)d_ws;
  size_t off = 0;
  auto alloc = [&](size_t b){ size_t o = off; off += (b + 255) & ~(size_t)255; return o; };
  size_t oA   = alloc((size_t)N*128*4);      // pre-GEMM: Hc32|RH16|CO|colTotal ; then hmid (bf16)
  size_t oB   = alloc((size_t)N*128*4);      // [0,12.8M): h0b/h1b bf16 ; [12.8M,25.6M): xp f32
  size_t oPL  = alloc((size_t)E*16);         // AoS payload {rv, c0, c1, pad}
  size_t oRK  = alloc((size_t)E*2);
  size_t oST  = alloc((size_t)(N2+1)*4);
  size_t oBS  = alloc((size_t)NB*4);
  size_t zbytes = (size_t)N2*4 + (size_t)G*128*4;
  size_t oZ   = alloc(zbytes);               // intra | genc
  size_t oIN  = oZ;
  size_t oGE  = oIN + (size_t)N2*4;
  size_t oD0  = alloc((size_t)N*4);
  size_t oD1  = alloc((size_t)N2*4);
  size_t oWsp = alloc((size_t)(16384*2 + 16384*2 + 32768*2 + 32768*2)*2);

  // chunked-histogram scratch lives inside oA (dead before first GEMM writes hmid)
  size_t aoff = oA;
  auto suballoc = [&](size_t b){ size_t o = aoff; aoff += (b + 255) & ~(size_t)255; return o; };
  unsigned*       Hc32 = (unsigned*)      (ws + suballoc((size_t)NCHK*(N2/4)*4));
  unsigned short* RH16 = (unsigned short*)(ws + suballoc((size_t)NCHK*N2*2));
  unsigned short* CO   = (unsigned short*)(ws + suballoc((size_t)NCHK*N2*2));
  int*      colTotal   = (int*)           (ws + suballoc((size_t)N2*4));

  unsigned short* hmid = (unsigned short*)(ws + oA);     // 50000x128 or 25000x256 bf16
  unsigned* h0b = (unsigned*)(ws + oB);                  // 50000x128 bf16 (as uints)
  unsigned* h1b = (unsigned*)(ws + oB);                  // 25000x128 bf16 (h0b dead)
  float* xp     = (float*)(ws + oB + (size_t)N2*128*4);  // 25000x128 f32
  uint4* payload= (uint4*)(ws + oPL);
  unsigned short* lrank = (unsigned short*)(ws + oRK);
  int*   starts = (int*)(ws + oST);
  int*   bsum   = (int*)(ws + oBS);
  unsigned* intra = (unsigned*)(ws + oIN);
  unsigned* genc= (unsigned*)(ws + oGE);
  float* dis0   = (float*)(ws + oD0);
  float* dis1   = (float*)(ws + oD1);
  short* l0W1h  = (short*)(ws + oWsp);
  short* l0W1l  = l0W1h + 16384;
  short* l0W2h  = l0W1l + 16384;
  short* l0W2l  = l0W2h + 16384;
  short* l1W1h  = l0W2l + 16384;
  short* l1W1l  = l1W1h + 32768;
  short* l1W2h  = l1W1l + 32768;
  short* l1W2l  = l1W2h + 32768;

  hipMemsetAsync(ws + oZ, 0, zbytes, stream);

  prep_all_kernel<<<96, 256, 0, stream>>>(l0_W1, l0_W2, l1_W1, l1_W2,
                                          l0W1h, l0W1l, l0W2h, l0W2l,
                                          l1W1h, l1W1l, l1W2h, l1W2l);

  hist_kernel<<<NCHK, 512, 0, stream>>>(ei, lrank, Hc32, RH16, intra, E, CS, N2);
  co_scan_kernel<<<(N2/4+255)/256, 256, 0, stream>>>(Hc32, CO, colTotal, N2);
  dis_kernel<<<(N2+255)/256, 256, 0, stream>>>(RH16, intra, dis0, dis1, N2);
  scan_partial_kernel<<<NB, 256, 0, stream>>>(colTotal, bsum, N2);
  scan_bsums_kernel<<<1, 64, 0, stream>>>(bsum, NB);
  scan_final_kernel<<<NB, 256, 0, stream>>>(colTotal, bsum, starts, N2);
  fill_kernel<<<(E+255)/256, 256, 0, stream>>>(ei, ea, l0_We, l0_be, l1_We, l1_be,
                                               starts, lrank, CO, payload, E, CS, N2);

  // MLP0: x (f32) -> hmid bf16 -> h0b (bf16, dis0-folded)
  gemm_split<8,0><<<(N+63)/64, 256, 0, stream>>>(x, l0W1h, l0W1l, l0_b1, l0_s, l0_t, nullptr, hmid, N, 128, 3);
  gemm_split<8,1><<<(N+63)/64, 256, 0, stream>>>(hmid, l0W2h, l0W2l, l0_b2, nullptr, nullptr, dis0, h0b, N, 128, 6);
  // aggregate layer0 fused with pair pool -> xp
  mp0_kernel<<<(N2+3)/4, 256, 0, stream>>>(starts, payload, dis0, h0b, origin, l0_We, l0_be, xp, N2);
  // MLP1: xp (f32) -> hmid bf16 (25000x256) -> h1b (bf16, dis1-folded)
  gemm_split<16,0><<<(N2+63)/64, 256, 0, stream>>>(xp, l1W1h, l1W1l, l1_b1, l1_s, l1_t, nullptr, hmid, N2, 128, 3);
  gemm_split<8,1><<<(N2+63)/64, 256, 0, stream>>>(hmid, l1W2h, l1W2l, l1_b2, nullptr, nullptr, dis1, h1b, N2, 256, 6);
  // aggregate layer1 + block-reduced global max pool
  mp1_kernel<<<(N2+3)/4, 256, 0, stream>>>(starts, payload, dis1, h1b, l1_We, l1_be, batchp, genc, N2);
  // head
  head_kernel<<<1, 256, 0, stream>>>(genc, hd_W1, hd_b1, hd_s, hd_t, hd_W2, hd_b2, (float*)d_out);
}